// Round 3
// baseline (450.022 us; speedup 1.0000x reference)
//
#include <hip/hip_runtime.h>
#include <hip/hip_bf16.h>
#include <hip/hip_fp8.h>

// ---------------------------------------------------------------------------
// GRACE contrastive loss, MI355X.
//  out = mean_k 0.5*(ln d1_k + ln d2_k) - 2*s12[k,k]
// With M=[n1;n2] (24576x256) everything is row sums of exp(M M^T / tau)
// split by j-half, plus diagonal probes.
//
// R9: break the MFMA->exp dependency chain. R6/R8 both sat at
// MfmaUtil*dur == 66us (the MX-fp8 matrix floor): per nj the wave issued
// 8 MFMA then 16 exp2 OF THOSE RESULTS -> in-order issue serializes
// matrix (276cy) + trans (~130cy) per nj, and barrier-locked waves phase-
// align so cross-wave overlap never materializes (R8: 12 waves/CU, util
// DROPPED to 35%). Fix: acc ping-pong — MFMAs write acc[nj&1] while the
// interleaved exp2s consume acc[(nj&1)^1] (previous nj, data-ready), one
// MFMA : two exps in program order, so exps fill the inter-MFMA issue
// gaps. acc[1] seeded with -3e38 (exp2 -> 0) so nj0 of jt0 is a no-op;
// final buffer flushed after the loop. Stage addresses precomputed as 4
// per-lane u32 offsets (kills per-jt mul/xor, trims the R8 spill source).
// Geometry unchanged from R8: 768 blocks (3/CU), 4 waves x 64r x 64c,
// 2x16KB LDS double buffer, one barrier per jt, launch_bounds(256,3).
// ---------------------------------------------------------------------------

#define NROWS 12288
#define TWO_N 24576
#define KDIM 256
#define BM 128
#define BN 128
#define BK 32
#define NCHUNK 8
#define JCHUNK (TWO_N / NCHUNK) /* 3072 */
#define BMS 256                 /* sim rows per block */
#define BJS 64                  /* sim cols per jt tile */
#define JTILES_S (JCHUNK / BJS) /* 48 */
#define FB 48                   /* finalize partial blocks */
#define LOG2E 1.4426950408889634f
#define SIMSCALE 1.6986436f     /* sqrt(2*log2(e)); acc = (1/tau)*log2e*s */
#define LN2F 0.6931471805599453f

#if __has_builtin(__builtin_amdgcn_exp2f)
#define EXP2F(x) __builtin_amdgcn_exp2f(x)
#else
#define EXP2F(x) exp2f(x)
#endif

typedef __bf16 bf16x8 __attribute__((ext_vector_type(8)));
typedef __bf16 bf16x4v __attribute__((ext_vector_type(4)));
typedef float f32x4 __attribute__((ext_vector_type(4)));
typedef int i32x4 __attribute__((ext_vector_type(4)));
typedef int i32x8 __attribute__((ext_vector_type(8)));
typedef unsigned char uchar;

typedef const __attribute__((address_space(1))) void* gptr_t;
typedef __attribute__((address_space(3))) void* lptr_t;

// ======== legacy 128x128 bf16 GEMM core (proj1/proj2 only) ================
__device__ __forceinline__ void stage_slab(const __bf16* g, int row0, int kelem,
                                           __bf16* lds, int w, int l) {
#pragma unroll
  for (int t = 0; t < 2; ++t) {
    int chunk = w * 2 + t;
    int r = chunk * 16 + (l >> 2);
    int c = l & 3;
    int src = c ^ (r & 3);
    const __bf16* ga = g + (size_t)(row0 + r) * KDIM + kelem + src * 8;
    __bf16* la = lds + chunk * 512;
    __builtin_amdgcn_global_load_lds((gptr_t)ga, (lptr_t)la, 16, 0, 0);
  }
}

__device__ __forceinline__ bf16x8 read_frag(const __bf16* lds, int rowbase,
                                            int tile, int l) {
  int r = rowbase + tile * 16 + (l & 15);
  int q = l >> 4;
  int blk = q ^ (r & 3);
  return *(const bf16x8*)(lds + r * 32 + blk * 8);
}

__device__ __forceinline__ void gemm_tile_core(const __bf16* A, int arow0,
                                               const __bf16* B, int brow0,
                                               __bf16* As, __bf16* Bs,
                                               f32x4 (&acc)[4][4], int w, int l) {
  const int warow = (w >> 1) * 64;
  const int wbrow = (w & 1) * 64;
#pragma unroll
  for (int ks = 0; ks < KDIM / BK; ++ks) {
    __syncthreads();
    stage_slab(A, arow0, ks * BK, As, w, l);
    stage_slab(B, brow0, ks * BK, Bs, w, l);
    __syncthreads();
    bf16x8 aF[4], bF[4];
#pragma unroll
    for (int mi = 0; mi < 4; ++mi) aF[mi] = read_frag(As, warow, mi, l);
#pragma unroll
    for (int ni = 0; ni < 4; ++ni) bF[ni] = read_frag(Bs, wbrow, ni, l);
#pragma unroll
    for (int mi = 0; mi < 4; ++mi)
#pragma unroll
      for (int ni = 0; ni < 4; ++ni)
        acc[mi][ni] = __builtin_amdgcn_mfma_f32_16x16x32_bf16(
            aF[mi], bF[ni], acc[mi][ni], 0, 0, 0);
  }
}

// ---------------------------------------------------------------------------
// one launch: cast z1, z2, W1, W2 to bf16 (float4 granules)
__global__ void cast_all_kernel(const float* __restrict__ z1,
                                const float* __restrict__ z2,
                                const float* __restrict__ W1,
                                const float* __restrict__ W2,
                                __bf16* __restrict__ Zb,
                                __bf16* __restrict__ W1b,
                                __bf16* __restrict__ W2b) {
  const int n4z = NROWS * KDIM / 4;  // 786432
  const int n4w = KDIM * KDIM / 4;   // 16384
  int i = blockIdx.x * blockDim.x + threadIdx.x;
  const float* src;
  __bf16* dst;
  int j;
  if (i < n4z) {
    src = z1; dst = Zb; j = i;
  } else if (i < 2 * n4z) {
    src = z2; dst = Zb + (size_t)NROWS * KDIM; j = i - n4z;
  } else if (i < 2 * n4z + n4w) {
    src = W1; dst = W1b; j = i - 2 * n4z;
  } else if (i < 2 * n4z + 2 * n4w) {
    src = W2; dst = W2b; j = i - 2 * n4z - n4w;
  } else {
    return;
  }
  float4 v = *(const float4*)(src + (size_t)j * 4);
  bf16x4v o;
  o[0] = (__bf16)v.x; o[1] = (__bf16)v.y; o[2] = (__bf16)v.z; o[3] = (__bf16)v.w;
  *(bf16x4v*)(dst + (size_t)j * 4) = o;
}

// T = ELU(Z @ W1^T + b1), stored bf16
__global__ __launch_bounds__(256, 2) void proj1_kernel(
    const __bf16* __restrict__ Zb, const __bf16* __restrict__ W1b,
    const float* __restrict__ b1, __bf16* __restrict__ Tb) {
  __shared__ __align__(16) __bf16 As[BM * BK];
  __shared__ __align__(16) __bf16 Bs[BN * BK];
  int w = threadIdx.x >> 6, l = threadIdx.x & 63;
  int i0 = blockIdx.x * BM, j0 = blockIdx.y * BN;
  int warow = (w >> 1) * 64, wbrow = (w & 1) * 64;
  f32x4 acc[4][4] = {};
  gemm_tile_core(Zb, i0, W1b, j0, As, Bs, acc, w, l);
  float bias[4];
#pragma unroll
  for (int ni = 0; ni < 4; ++ni) bias[ni] = b1[j0 + wbrow + ni * 16 + (l & 15)];
#pragma unroll
  for (int mi = 0; mi < 4; ++mi)
#pragma unroll
    for (int ni = 0; ni < 4; ++ni)
#pragma unroll
      for (int v = 0; v < 4; ++v) {
        int row = i0 + warow + mi * 16 + (l >> 4) * 4 + v;
        int col = j0 + wbrow + ni * 16 + (l & 15);
        float x = acc[mi][ni][v] + bias[ni];
        x = x > 0.f ? x : (EXP2F(x * LOG2E) - 1.f);  // ELU
        Tb[(size_t)row * KDIM + col] = (__bf16)x;
      }
}

// H = T @ W2^T + b2 (fp32), plus per-row sum of squares via atomics
__global__ __launch_bounds__(256, 2) void proj2_kernel(
    const __bf16* __restrict__ Tb, const __bf16* __restrict__ W2b,
    const float* __restrict__ b2, float* __restrict__ H,
    float* __restrict__ SS) {
  __shared__ __align__(16) __bf16 As[BM * BK];
  __shared__ __align__(16) __bf16 Bs[BN * BK];
  int w = threadIdx.x >> 6, l = threadIdx.x & 63;
  int i0 = blockIdx.x * BM, j0 = blockIdx.y * BN;
  int warow = (w >> 1) * 64, wbrow = (w & 1) * 64;
  f32x4 acc[4][4] = {};
  gemm_tile_core(Tb, i0, W2b, j0, As, Bs, acc, w, l);
  float bias[4];
#pragma unroll
  for (int ni = 0; ni < 4; ++ni) bias[ni] = b2[j0 + wbrow + ni * 16 + (l & 15)];
  float ss[4][4] = {};
#pragma unroll
  for (int mi = 0; mi < 4; ++mi)
#pragma unroll
    for (int ni = 0; ni < 4; ++ni)
#pragma unroll
      for (int v = 0; v < 4; ++v) {
        int row = i0 + warow + mi * 16 + (l >> 4) * 4 + v;
        int col = j0 + wbrow + ni * 16 + (l & 15);
        float x = acc[mi][ni][v] + bias[ni];
        H[(size_t)row * KDIM + col] = x;
        ss[mi][v] += x * x;
      }
#pragma unroll
  for (int mi = 0; mi < 4; ++mi)
#pragma unroll
    for (int v = 0; v < 4; ++v) {
      float x = ss[mi][v];
      x += __shfl_xor(x, 1, 64);
      x += __shfl_xor(x, 2, 64);
      x += __shfl_xor(x, 4, 64);
      x += __shfl_xor(x, 8, 64);
      if ((l & 15) == 0)
        atomicAdd(&SS[i0 + warow + mi * 16 + (l >> 4) * 4 + v], x);
    }
}

// pack 4 floats -> 4 fp8 e4m3 bytes
__device__ __forceinline__ unsigned int pack4_fp8(float a, float b, float c,
                                                  float d) {
#if __has_builtin(__builtin_amdgcn_cvt_pk_fp8_f32)
  int v = 0;
  v = __builtin_amdgcn_cvt_pk_fp8_f32(a, b, v, false);
  v = __builtin_amdgcn_cvt_pk_fp8_f32(c, d, v, true);
  return (unsigned int)v;
#else
  __hip_fp8_e4m3 qa(a), qb(b), qc(c), qd(d);
  return (unsigned int)qa.__x | ((unsigned int)qb.__x << 8) |
         ((unsigned int)qc.__x << 16) | ((unsigned int)qd.__x << 24);
#endif
}

// Nq = fp8(H * rsqrt(SS[row]) * SIMSCALE) — 8 elements per thread.
// SIMSCALE folds the (1/tau)*log2(e) exponent scale into the data:
// dot(Nq_i, Nq_j) = 2.8854 * cos_ij, so exp2(acc) = exp(cos/tau).
__global__ void norm_kernel(const float* __restrict__ H,
                            const float* __restrict__ SS,
                            uchar* __restrict__ Nq) {
  int i = blockIdx.x * blockDim.x + threadIdx.x;
  size_t idx = (size_t)i * 8;
  if (idx >= (size_t)TWO_N * KDIM) return;
  int row = (int)(idx >> 8);
  float inv = rsqrtf(SS[row]) * SIMSCALE;
  float4 h0 = *(const float4*)(H + idx);
  float4 h1 = *(const float4*)(H + idx + 4);
  uint2 o;
  o.x = pack4_fp8(h0.x * inv, h0.y * inv, h0.z * inv, h0.w * inv);
  o.y = pack4_fp8(h1.x * inv, h1.y * inv, h1.z * inv, h1.w * inv);
  *(uint2*)(Nq + idx) = o;
}

// ======== R9 sim kernel: acc ping-pong, exp under the MFMA shadow ==========
// grid = 768 1D blocks (3/CU). chunk = blockIdx&7 (XCD-pinned j-range),
// itile = blockIdx>>3 (256 A-rows). 4 waves x (64 rows x 64 cols).
// aF 64 VGPR + acc 2x16 + rs 16 + bF 16 ~= 150 regs, (256,3) cap ~170.
// Per nj: MFMAs -> acc[nj&1]; exp2s of acc[(nj&1)^1] (previous nj, ready)
// interleaved 1 MFMA : 2 exps so the trans work issues inside the matrix
// pipe's ~34cy per-MFMA shadow. acc[1] seeded -3e38 => exp2 = 0 on the
// first iteration; flushed after the loop.
__global__ __launch_bounds__(256, 3) void sim_kernel(
    const uchar* __restrict__ Nq, float* __restrict__ Rlow,
    float* __restrict__ Rhigh, float* __restrict__ Dsame,
    float* __restrict__ Dcross) {
  __shared__ __align__(16) uchar Bs[2][BJS * KDIM];  // 2 x 16KB
  int tid = threadIdx.x;
  int w = tid >> 6, l = tid & 63;
  int q = l >> 4;
  int b = blockIdx.x;
  int chunk = b & 7;           // XCD id under round-robin dispatch
  int i0 = (b >> 3) * BMS;
  int jbase = chunk * JCHUNK;
  int warow = w * 64;          // this wave owns rows [warow, warow+64)

  // per-lane constant staging offsets (source-side XOR swizzle: LDS slot c
  // of row r holds global 16B-block c ^ (r&15)); jt advances by 16KB.
  unsigned off0[4];
#pragma unroll
  for (int t = 0; t < 4; ++t) {
    int ch = w * 4 + t;            // wave-uniform chunk 0..15 (1KB each)
    int r = ch * 4 + (l >> 4);     // row 0..63 (4 rows per chunk)
    int c = l & 15;                // dest 16B-block slot
    int src = c ^ (r & 15);        // global k-block landing in slot c
    off0[t] = (unsigned)((jbase + r) * KDIM + src * 16);
  }
  auto stage = [&](int jt, int bi) {
    unsigned jo = (unsigned)(jt * (BJS * KDIM));
#pragma unroll
    for (int t = 0; t < 4; ++t) {
      const uchar* ga = Nq + (size_t)(off0[t] + jo);
      uchar* la = Bs[bi] + (w * 4 + t) * 1024;  // wave-uniform base
      __builtin_amdgcn_global_load_lds((gptr_t)ga, (lptr_t)la, 16, 0, 0);
    }
  };

  // ---- A fragments in registers: aF[mi][hf], 8 x i32x8 = 64 VGPRs ----
  // f8f6f4 16x16x128 A layout: lane holds row (l&15), k = q*32 + 0..31.
  i32x8 aF[4][2];
#pragma unroll
  for (int mi = 0; mi < 4; ++mi) {
    const uchar* ap =
        Nq + (size_t)(i0 + warow + mi * 16 + (l & 15)) * KDIM + q * 32;
#pragma unroll
    for (int hf = 0; hf < 2; ++hf)
      aF[mi][hf] = *(const i32x8*)(ap + hf * 128);
  }

  float rs[4][4] = {};  // running row sums (per mi, per v)

  // ping-pong accumulators; acc[1] seeded so the first deferred exp adds 0
  f32x4 acc[2][4];
#pragma unroll
  for (int mi = 0; mi < 4; ++mi)
    acc[1][mi] = (f32x4){-3.0e38f, -3.0e38f, -3.0e38f, -3.0e38f};

  stage(0, 0);  // prologue

  for (int jt = 0; jt < JTILES_S; ++jt) {
    int bi = jt & 1;
    __syncthreads();                       // stage(jt) done; prev readers done
    if (jt + 1 < JTILES_S) stage(jt + 1, bi ^ 1);  // drains at NEXT barrier

    int j0 = jbase + jt * BJS;
    // diagonal hits this wave's 64-row band only when col-tile aligns with it
    bool dsame = (j0 == i0 + warow);
    bool dcross = (j0 == i0 + warow + NROWS);

#pragma unroll
    for (int nj = 0; nj < 4; ++nj) {
      const int cur = nj & 1, prv = cur ^ 1;
      int row = nj * 16 + (l & 15);
      int rx = row & 15;
      const uchar* base = Bs[bi] + row * KDIM;
      // B fragments for both K-halves up front
      i32x8 bF[2];
#pragma unroll
      for (int hf = 0; hf < 2; ++hf) {
        int kb = hf * 8 + 2 * q;                 // even global block index
        i32x4 lo = *(const i32x4*)(base + ((kb ^ rx) << 4));
        i32x4 hi = *(const i32x4*)(base + (((kb + 1) ^ rx) << 4));
        bF[hf] = __builtin_shufflevector(lo, hi, 0, 1, 2, 3, 4, 5, 6, 7);
      }
#pragma unroll
      for (int mi = 0; mi < 4; ++mi)
        acc[cur][mi] = (f32x4){0.f, 0.f, 0.f, 0.f};
      // 8 MFMAs into acc[cur]; 16 exps of acc[prv] interleaved 1:2 so the
      // trans/VALU work issues while the matrix pipe is busy.
#pragma unroll
      for (int hf = 0; hf < 2; ++hf)
#pragma unroll
        for (int mi = 0; mi < 4; ++mi) {
          acc[cur][mi] = __builtin_amdgcn_mfma_scale_f32_16x16x128_f8f6f4(
              aF[mi][hf], bF[hf], acc[cur][mi], 0, 0, 0, 0x7F7F7F7F, 0,
              0x7F7F7F7F);
          const int e0 = (hf * 4 + mi) * 2, e1 = e0 + 1;
          rs[e0 >> 2][e0 & 3] += EXP2F(acc[prv][e0 >> 2][e0 & 3]);
          rs[e1 >> 2][e1 & 3] += EXP2F(acc[prv][e1 >> 2][e1 & 3]);
        }

      if (dsame | dcross) {       // wave-uniform, 2 of 48 jt iterations
        float* D = dsame ? Dsame : Dcross;
#pragma unroll
        for (int mi = 0; mi < 4; ++mi)
#pragma unroll
          for (int v = 0; v < 4; ++v) {
            int li = mi * 16 + q * 4 + v;     // within wave's 64 rows
            int lj = nj * 16 + (l & 15);      // within tile's 64 cols
            if (li == lj) D[i0 + warow + li] = acc[cur][mi][v];
          }
      }
    }
  }

  // flush the last nj's accumulator (lives in acc[1]: nj=3 -> index 1)
#pragma unroll
  for (int mi = 0; mi < 4; ++mi)
#pragma unroll
    for (int v = 0; v < 4; ++v)
      rs[mi][v] += EXP2F(acc[1][mi][v]);

  // cross-lane (16-wide) reduce, one atomicAdd per row per wave
  float* R = (chunk >= NCHUNK / 2) ? Rhigh : Rlow;
#pragma unroll
  for (int mi = 0; mi < 4; ++mi)
#pragma unroll
    for (int v = 0; v < 4; ++v) {
      float x = rs[mi][v];
      x += __shfl_xor(x, 1, 64);
      x += __shfl_xor(x, 2, 64);
      x += __shfl_xor(x, 4, 64);
      x += __shfl_xor(x, 8, 64);
      if ((l & 15) == 0)
        atomicAdd(&R[i0 + warow + mi * 16 + q * 4 + v], x);
    }
}

// Dsame/Dcross hold acc = (1/tau)*log2e * s. exp(s/tau) = exp2(acc);
// -2*s = -ln2 * acc.  48 blocks x 256 threads = 12288 rows exactly.
__global__ void finalize1_kernel(const float* __restrict__ Rlow,
                                 const float* __restrict__ Rhigh,
                                 const float* __restrict__ Dsame,
                                 const float* __restrict__ Dcross,
                                 float* __restrict__ partial) {
  __shared__ float red[256];
  int k = blockIdx.x * 256 + threadIdx.x;
  float d1 = Rlow[k] + Rhigh[k] - EXP2F(Dsame[k]);
  float d2 = Rhigh[NROWS + k] + Rlow[NROWS + k] - EXP2F(Dsame[NROWS + k]);
  float acc = 0.5f * (logf(d1) + logf(d2)) - LN2F * Dcross[k];
  red[threadIdx.x] = acc;
  __syncthreads();
  for (int s = 128; s > 0; s >>= 1) {
    if (threadIdx.x < s) red[threadIdx.x] += red[threadIdx.x + s];
    __syncthreads();
  }
  if (threadIdx.x == 0) partial[blockIdx.x] = red[0];
}

__global__ void finalize2_kernel(const float* __restrict__ partial,
                                 float* __restrict__ out) {
  float x = (threadIdx.x < FB) ? partial[threadIdx.x] : 0.f;
#pragma unroll
  for (int s = 32; s > 0; s >>= 1) x += __shfl_down(x, s, 64);
  if (threadIdx.x == 0) out[0] = x / (float)NROWS;
}

// ---------------------------------------------------------------------------
extern "C" void kernel_launch(void* const* d_in, const int* in_sizes, int n_in,
                              void* d_out, int out_size, void* d_ws,
                              size_t ws_size, hipStream_t stream) {
  const float* z1 = (const float*)d_in[0];
  const float* z2 = (const float*)d_in[1];
  const float* W1 = (const float*)d_in[2];
  const float* b1 = (const float*)d_in[3];
  const float* W2 = (const float*)d_in[4];
  const float* b2 = (const float*)d_in[5];
  float* out = (float*)d_out;

  char* ws = (char*)d_ws;
  size_t off = 0;
  auto alloc = [&](size_t bytes) -> void* {
    void* p = ws + off;
    off += (bytes + 255) & ~(size_t)255;
    return p;
  };
  __bf16* Zb   = (__bf16*)alloc((size_t)TWO_N * KDIM * 2); // reused as Nq
  __bf16* W1b  = (__bf16*)alloc((size_t)KDIM * KDIM * 2);
  __bf16* W2b  = (__bf16*)alloc((size_t)KDIM * KDIM * 2);
  __bf16* Tb   = (__bf16*)alloc((size_t)TWO_N * KDIM * 2);
  float*  H    = (float*)alloc((size_t)TWO_N * KDIM * 4);
  float*  SS   = (float*)alloc((size_t)TWO_N * 4);
  float*  Rlow = (float*)alloc((size_t)TWO_N * 4);
  float*  Rhigh= (float*)alloc((size_t)TWO_N * 4);
  float*  Dsame= (float*)alloc((size_t)TWO_N * 4);
  float*  Dcross=(float*)alloc((size_t)NROWS * 4);
  float*  partial=(float*)alloc((size_t)FB * 4);
  uchar*  Nq = (uchar*)Zb;  // Zb dead after proj1; fp8 fits in its footprint

  hipMemsetAsync(SS, 0, (size_t)TWO_N * 4, stream);
  hipMemsetAsync(Rlow, 0, (size_t)TWO_N * 4, stream);
  hipMemsetAsync(Rhigh, 0, (size_t)TWO_N * 4, stream);

  int n4z = NROWS * KDIM / 4;   // 786432
  int n4w = KDIM * KDIM / 4;    // 16384
  int n4all = 2 * n4z + 2 * n4w;
  cast_all_kernel<<<(n4all + 255) / 256, 256, 0, stream>>>(z1, z2, W1, W2, Zb,
                                                           W1b, W2b);

  proj1_kernel<<<dim3(TWO_N / BM, KDIM / BN), 256, 0, stream>>>(Zb, W1b, b1, Tb);
  proj2_kernel<<<dim3(TWO_N / BM, KDIM / BN), 256, 0, stream>>>(Tb, W2b, b2, H, SS);

  int n8n = TWO_N * KDIM / 8;   // 786432
  norm_kernel<<<(n8n + 255) / 256, 256, 0, stream>>>(H, SS, Nq);

  sim_kernel<<<(TWO_N / BMS) * NCHUNK, 256, 0, stream>>>(Nq, Rlow, Rhigh,
                                                         Dsame, Dcross);
  finalize1_kernel<<<FB, 256, 0, stream>>>(Rlow, Rhigh, Dsame, Dcross, partial);
  finalize2_kernel<<<1, 64, 0, stream>>>(partial, out);
}

// Round 4
// 264.927 us; speedup vs baseline: 1.6987x; 1.6987x over previous
//
#include <hip/hip_runtime.h>
#include <hip/hip_bf16.h>
#include <hip/hip_fp8.h>

// ---------------------------------------------------------------------------
// GRACE contrastive loss, MI355X.
//  out = mean_k 0.5*(ln d1_k + ln d2_k) - 2*s12[k,k]
// With M=[n1;n2] (24576x256) everything is row sums of exp(M M^T / tau)
// split by j-half, plus diagonal probes.
//
// R10: ping-pong interleave on the NO-SPILL geometry. R9's acc ping-pong
// was correct but ran under launch_bounds(256,3), whose arch/AGPR split
// caps arch VGPRs at 84 (R8+R9 both report 84); the extra 32-reg live set
// spilled -> WRITE 103MB scratch, MfmaUtil 17.6%. The interleave never
// actually executed from registers. R10 = R6 geometry (BM=128 rows,
// BJ=128 cols/jt, 2x2 wave grid 64x64, 2x32KB LDS, launch_bounds(256,2),
// grid 1536 = 3 exact residency rounds, VGPR budget 256 -> no spill) +
// R9's interleave: per nj, 8 MFMAs write acc[nj&1] while 16 exp2s of
// acc[(nj&1)^1] (previous nj, data-ready) are interleaved 1 MFMA : 2 exps
// so trans/VALU work issues inside the matrix pipe's shadow. acc[1]
// seeded -3e38 (exp2 -> 0) so the first deferred batch is a no-op; final
// buffer flushed after the loop. Stage offsets precomputed per-lane.
// ---------------------------------------------------------------------------

#define NROWS 12288
#define TWO_N 24576
#define KDIM 256
#define BM 128
#define BN 128
#define BK 32
#define BJ 128
#define NCHUNK 8
#define JCHUNK (TWO_N / NCHUNK) /* 3072 */
#define JTILES (JCHUNK / BJ)    /* 24 */
#define FB 48                   /* finalize partial blocks */
#define LOG2E 1.4426950408889634f
#define SIMSCALE 1.6986436f     /* sqrt(2*log2(e)); acc = (1/tau)*log2e*s */
#define LN2F 0.6931471805599453f

#if __has_builtin(__builtin_amdgcn_exp2f)
#define EXP2F(x) __builtin_amdgcn_exp2f(x)
#else
#define EXP2F(x) exp2f(x)
#endif

typedef __bf16 bf16x8 __attribute__((ext_vector_type(8)));
typedef __bf16 bf16x4v __attribute__((ext_vector_type(4)));
typedef float f32x4 __attribute__((ext_vector_type(4)));
typedef int i32x4 __attribute__((ext_vector_type(4)));
typedef int i32x8 __attribute__((ext_vector_type(8)));
typedef unsigned char uchar;

typedef const __attribute__((address_space(1))) void* gptr_t;
typedef __attribute__((address_space(3))) void* lptr_t;

// ======== legacy 128x128 bf16 GEMM core (proj1/proj2 only) ================
__device__ __forceinline__ void stage_slab(const __bf16* g, int row0, int kelem,
                                           __bf16* lds, int w, int l) {
#pragma unroll
  for (int t = 0; t < 2; ++t) {
    int chunk = w * 2 + t;
    int r = chunk * 16 + (l >> 2);
    int c = l & 3;
    int src = c ^ (r & 3);
    const __bf16* ga = g + (size_t)(row0 + r) * KDIM + kelem + src * 8;
    __bf16* la = lds + chunk * 512;
    __builtin_amdgcn_global_load_lds((gptr_t)ga, (lptr_t)la, 16, 0, 0);
  }
}

__device__ __forceinline__ bf16x8 read_frag(const __bf16* lds, int rowbase,
                                            int tile, int l) {
  int r = rowbase + tile * 16 + (l & 15);
  int q = l >> 4;
  int blk = q ^ (r & 3);
  return *(const bf16x8*)(lds + r * 32 + blk * 8);
}

__device__ __forceinline__ void gemm_tile_core(const __bf16* A, int arow0,
                                               const __bf16* B, int brow0,
                                               __bf16* As, __bf16* Bs,
                                               f32x4 (&acc)[4][4], int w, int l) {
  const int warow = (w >> 1) * 64;
  const int wbrow = (w & 1) * 64;
#pragma unroll
  for (int ks = 0; ks < KDIM / BK; ++ks) {
    __syncthreads();
    stage_slab(A, arow0, ks * BK, As, w, l);
    stage_slab(B, brow0, ks * BK, Bs, w, l);
    __syncthreads();
    bf16x8 aF[4], bF[4];
#pragma unroll
    for (int mi = 0; mi < 4; ++mi) aF[mi] = read_frag(As, warow, mi, l);
#pragma unroll
    for (int ni = 0; ni < 4; ++ni) bF[ni] = read_frag(Bs, wbrow, ni, l);
#pragma unroll
    for (int mi = 0; mi < 4; ++mi)
#pragma unroll
      for (int ni = 0; ni < 4; ++ni)
        acc[mi][ni] = __builtin_amdgcn_mfma_f32_16x16x32_bf16(
            aF[mi], bF[ni], acc[mi][ni], 0, 0, 0);
  }
}

// ---------------------------------------------------------------------------
// one launch: cast z1, z2, W1, W2 to bf16 (float4 granules)
__global__ void cast_all_kernel(const float* __restrict__ z1,
                                const float* __restrict__ z2,
                                const float* __restrict__ W1,
                                const float* __restrict__ W2,
                                __bf16* __restrict__ Zb,
                                __bf16* __restrict__ W1b,
                                __bf16* __restrict__ W2b) {
  const int n4z = NROWS * KDIM / 4;  // 786432
  const int n4w = KDIM * KDIM / 4;   // 16384
  int i = blockIdx.x * blockDim.x + threadIdx.x;
  const float* src;
  __bf16* dst;
  int j;
  if (i < n4z) {
    src = z1; dst = Zb; j = i;
  } else if (i < 2 * n4z) {
    src = z2; dst = Zb + (size_t)NROWS * KDIM; j = i - n4z;
  } else if (i < 2 * n4z + n4w) {
    src = W1; dst = W1b; j = i - 2 * n4z;
  } else if (i < 2 * n4z + 2 * n4w) {
    src = W2; dst = W2b; j = i - 2 * n4z - n4w;
  } else {
    return;
  }
  float4 v = *(const float4*)(src + (size_t)j * 4);
  bf16x4v o;
  o[0] = (__bf16)v.x; o[1] = (__bf16)v.y; o[2] = (__bf16)v.z; o[3] = (__bf16)v.w;
  *(bf16x4v*)(dst + (size_t)j * 4) = o;
}

// T = ELU(Z @ W1^T + b1), stored bf16
__global__ __launch_bounds__(256, 2) void proj1_kernel(
    const __bf16* __restrict__ Zb, const __bf16* __restrict__ W1b,
    const float* __restrict__ b1, __bf16* __restrict__ Tb) {
  __shared__ __align__(16) __bf16 As[BM * BK];
  __shared__ __align__(16) __bf16 Bs[BN * BK];
  int w = threadIdx.x >> 6, l = threadIdx.x & 63;
  int i0 = blockIdx.x * BM, j0 = blockIdx.y * BN;
  int warow = (w >> 1) * 64, wbrow = (w & 1) * 64;
  f32x4 acc[4][4] = {};
  gemm_tile_core(Zb, i0, W1b, j0, As, Bs, acc, w, l);
  float bias[4];
#pragma unroll
  for (int ni = 0; ni < 4; ++ni) bias[ni] = b1[j0 + wbrow + ni * 16 + (l & 15)];
#pragma unroll
  for (int mi = 0; mi < 4; ++mi)
#pragma unroll
    for (int ni = 0; ni < 4; ++ni)
#pragma unroll
      for (int v = 0; v < 4; ++v) {
        int row = i0 + warow + mi * 16 + (l >> 4) * 4 + v;
        int col = j0 + wbrow + ni * 16 + (l & 15);
        float x = acc[mi][ni][v] + bias[ni];
        x = x > 0.f ? x : (EXP2F(x * LOG2E) - 1.f);  // ELU
        Tb[(size_t)row * KDIM + col] = (__bf16)x;
      }
}

// H = T @ W2^T + b2 (fp32), plus per-row sum of squares via atomics
__global__ __launch_bounds__(256, 2) void proj2_kernel(
    const __bf16* __restrict__ Tb, const __bf16* __restrict__ W2b,
    const float* __restrict__ b2, float* __restrict__ H,
    float* __restrict__ SS) {
  __shared__ __align__(16) __bf16 As[BM * BK];
  __shared__ __align__(16) __bf16 Bs[BN * BK];
  int w = threadIdx.x >> 6, l = threadIdx.x & 63;
  int i0 = blockIdx.x * BM, j0 = blockIdx.y * BN;
  int warow = (w >> 1) * 64, wbrow = (w & 1) * 64;
  f32x4 acc[4][4] = {};
  gemm_tile_core(Tb, i0, W2b, j0, As, Bs, acc, w, l);
  float bias[4];
#pragma unroll
  for (int ni = 0; ni < 4; ++ni) bias[ni] = b2[j0 + wbrow + ni * 16 + (l & 15)];
  float ss[4][4] = {};
#pragma unroll
  for (int mi = 0; mi < 4; ++mi)
#pragma unroll
    for (int ni = 0; ni < 4; ++ni)
#pragma unroll
      for (int v = 0; v < 4; ++v) {
        int row = i0 + warow + mi * 16 + (l >> 4) * 4 + v;
        int col = j0 + wbrow + ni * 16 + (l & 15);
        float x = acc[mi][ni][v] + bias[ni];
        H[(size_t)row * KDIM + col] = x;
        ss[mi][v] += x * x;
      }
#pragma unroll
  for (int mi = 0; mi < 4; ++mi)
#pragma unroll
    for (int v = 0; v < 4; ++v) {
      float x = ss[mi][v];
      x += __shfl_xor(x, 1, 64);
      x += __shfl_xor(x, 2, 64);
      x += __shfl_xor(x, 4, 64);
      x += __shfl_xor(x, 8, 64);
      if ((l & 15) == 0)
        atomicAdd(&SS[i0 + warow + mi * 16 + (l >> 4) * 4 + v], x);
    }
}

// pack 4 floats -> 4 fp8 e4m3 bytes
__device__ __forceinline__ unsigned int pack4_fp8(float a, float b, float c,
                                                  float d) {
#if __has_builtin(__builtin_amdgcn_cvt_pk_fp8_f32)
  int v = 0;
  v = __builtin_amdgcn_cvt_pk_fp8_f32(a, b, v, false);
  v = __builtin_amdgcn_cvt_pk_fp8_f32(c, d, v, true);
  return (unsigned int)v;
#else
  __hip_fp8_e4m3 qa(a), qb(b), qc(c), qd(d);
  return (unsigned int)qa.__x | ((unsigned int)qb.__x << 8) |
         ((unsigned int)qc.__x << 16) | ((unsigned int)qd.__x << 24);
#endif
}

// Nq = fp8(H * rsqrt(SS[row]) * SIMSCALE) — 8 elements per thread.
// SIMSCALE folds the (1/tau)*log2(e) exponent scale into the data:
// dot(Nq_i, Nq_j) = 2.8854 * cos_ij, so exp2(acc) = exp(cos/tau).
__global__ void norm_kernel(const float* __restrict__ H,
                            const float* __restrict__ SS,
                            uchar* __restrict__ Nq) {
  int i = blockIdx.x * blockDim.x + threadIdx.x;
  size_t idx = (size_t)i * 8;
  if (idx >= (size_t)TWO_N * KDIM) return;
  int row = (int)(idx >> 8);
  float inv = rsqrtf(SS[row]) * SIMSCALE;
  float4 h0 = *(const float4*)(H + idx);
  float4 h1 = *(const float4*)(H + idx + 4);
  uint2 o;
  o.x = pack4_fp8(h0.x * inv, h0.y * inv, h0.z * inv, h0.w * inv);
  o.y = pack4_fp8(h1.x * inv, h1.y * inv, h1.z * inv, h1.w * inv);
  *(uint2*)(Nq + idx) = o;
}

// ======== R10 sim kernel: R6 geometry + acc ping-pong ======================
// grid = 1536 1D blocks (2/CU resident, 3 exact rounds). chunk = blockIdx&7
// (XCD-pinned j-range), itile = blockIdx>>3 (128 A-rows). 2x2 wave grid,
// 64 rows x 64 cols per wave. LDS 2x32KB double buffer, one barrier per jt.
// launch_bounds(256,2): 256-reg budget; aF 64 + acc 32 + rs 16 + bF 16
// + offs ~10 ~= 150 regs -> NO spill (R9's (256,3) split arch regs at 84
// and spilled the ping-pong live set -> 103MB scratch writes).
// Per nj: 8 MFMAs -> acc[nj&1]; 16 exp2s of acc[(nj&1)^1] interleaved
// 1 MFMA : 2 exps so trans issues under the matrix pipe.
__global__ __launch_bounds__(256, 2) void sim_kernel(
    const uchar* __restrict__ Nq, float* __restrict__ Rlow,
    float* __restrict__ Rhigh, float* __restrict__ Dsame,
    float* __restrict__ Dcross) {
  __shared__ __align__(16) uchar Bs[2][BJ * KDIM];  // 2 x 32KB
  int tid = threadIdx.x;
  int w = tid >> 6, l = tid & 63;
  int q = l >> 4;
  int b = blockIdx.x;
  int chunk = b & 7;           // XCD id under round-robin dispatch
  int i0 = (b >> 3) * BM;
  int jbase = chunk * JCHUNK;
  int warow = (w >> 1) * 64;   // A rows of this wave
  int wbcol = (w & 1) * 64;    // B cols of this wave

  // per-lane constant staging offsets (source-side XOR swizzle: LDS slot c
  // of row r holds global 16B-block c ^ (r&15)); jt advances by 32KB.
  unsigned off0[8];
#pragma unroll
  for (int t = 0; t < 8; ++t) {
    int ch = w * 8 + t;            // wave-uniform chunk 0..31 (1KB each)
    int r = ch * 4 + (l >> 4);     // row 0..127 (4 rows per chunk)
    int c = l & 15;                // dest 16B-block slot
    int src = c ^ (r & 15);        // global k-block landing in slot c
    off0[t] = (unsigned)((jbase + r) * KDIM + src * 16);
  }
  auto stage = [&](int jt, int bi) {
    unsigned jo = (unsigned)(jt * (BJ * KDIM));
#pragma unroll
    for (int t = 0; t < 8; ++t) {
      const uchar* ga = Nq + (size_t)(off0[t] + jo);
      uchar* la = Bs[bi] + (w * 8 + t) * 1024;  // wave-uniform base
      __builtin_amdgcn_global_load_lds((gptr_t)ga, (lptr_t)la, 16, 0, 0);
    }
  };

  // ---- A fragments in registers: aF[mi][hf], 8 x i32x8 = 64 VGPRs ----
  // f8f6f4 16x16x128 A layout: lane holds row (l&15), k = q*32 + 0..31.
  i32x8 aF[4][2];
#pragma unroll
  for (int mi = 0; mi < 4; ++mi) {
    const uchar* ap =
        Nq + (size_t)(i0 + warow + mi * 16 + (l & 15)) * KDIM + q * 32;
#pragma unroll
    for (int hf = 0; hf < 2; ++hf)
      aF[mi][hf] = *(const i32x8*)(ap + hf * 128);
  }

  float rs[4][4] = {};  // running row sums (per mi, per v)

  // ping-pong accumulators; acc[1] seeded so the first deferred exp adds 0
  f32x4 acc[2][4];
#pragma unroll
  for (int mi = 0; mi < 4; ++mi)
    acc[1][mi] = (f32x4){-3.0e38f, -3.0e38f, -3.0e38f, -3.0e38f};

  stage(0, 0);  // prologue

  for (int jt = 0; jt < JTILES; ++jt) {
    int bi = jt & 1;
    __syncthreads();                       // stage(jt) done; prev readers done
    if (jt + 1 < JTILES) stage(jt + 1, bi ^ 1);  // drains at NEXT barrier

    int j0 = jbase + jt * BJ;
    bool dsame = (j0 == i0);
    bool dcross = (j0 == i0 + NROWS);

#pragma unroll
    for (int nj = 0; nj < 4; ++nj) {
      const int cur = nj & 1, prv = cur ^ 1;
      int row = wbcol + nj * 16 + (l & 15);
      int rx = row & 15;
      const uchar* base = Bs[bi] + row * KDIM;
      // B fragments for both K-halves up front
      i32x8 bF[2];
#pragma unroll
      for (int hf = 0; hf < 2; ++hf) {
        int kb = hf * 8 + 2 * q;                 // even global block index
        i32x4 lo = *(const i32x4*)(base + ((kb ^ rx) << 4));
        i32x4 hi = *(const i32x4*)(base + (((kb + 1) ^ rx) << 4));
        bF[hf] = __builtin_shufflevector(lo, hi, 0, 1, 2, 3, 4, 5, 6, 7);
      }
#pragma unroll
      for (int mi = 0; mi < 4; ++mi)
        acc[cur][mi] = (f32x4){0.f, 0.f, 0.f, 0.f};
      // 8 MFMAs into acc[cur]; 16 exps of acc[prv] interleaved 1:2 so the
      // trans/VALU work issues while the matrix pipe is busy.
#pragma unroll
      for (int hf = 0; hf < 2; ++hf)
#pragma unroll
        for (int mi = 0; mi < 4; ++mi) {
          acc[cur][mi] = __builtin_amdgcn_mfma_scale_f32_16x16x128_f8f6f4(
              aF[mi][hf], bF[hf], acc[cur][mi], 0, 0, 0, 0x7F7F7F7F, 0,
              0x7F7F7F7F);
          const int e0 = (hf * 4 + mi) * 2, e1 = e0 + 1;
          rs[e0 >> 2][e0 & 3] += EXP2F(acc[prv][e0 >> 2][e0 & 3]);
          rs[e1 >> 2][e1 & 3] += EXP2F(acc[prv][e1 >> 2][e1 & 3]);
        }

      if (dsame | dcross) {       // wave-uniform, 2 of 24 jt iterations
        float* D = dsame ? Dsame : Dcross;
#pragma unroll
        for (int mi = 0; mi < 4; ++mi)
#pragma unroll
          for (int v = 0; v < 4; ++v) {
            int li = warow + mi * 16 + q * 4 + v;
            int lj = wbcol + nj * 16 + (l & 15);
            if (li == lj) D[i0 + li] = acc[cur][mi][v];
          }
      }
    }
  }

  // flush the last nj's accumulator (nj=3 wrote acc[1])
#pragma unroll
  for (int mi = 0; mi < 4; ++mi)
#pragma unroll
    for (int v = 0; v < 4; ++v)
      rs[mi][v] += EXP2F(acc[1][mi][v]);

  // cross-lane (16-wide) reduce, one atomicAdd per row per wave
  float* R = (chunk >= NCHUNK / 2) ? Rhigh : Rlow;
#pragma unroll
  for (int mi = 0; mi < 4; ++mi)
#pragma unroll
    for (int v = 0; v < 4; ++v) {
      float x = rs[mi][v];
      x += __shfl_xor(x, 1, 64);
      x += __shfl_xor(x, 2, 64);
      x += __shfl_xor(x, 4, 64);
      x += __shfl_xor(x, 8, 64);
      if ((l & 15) == 0)
        atomicAdd(&R[i0 + warow + mi * 16 + q * 4 + v], x);
    }
}

// Dsame/Dcross hold acc = (1/tau)*log2e * s. exp(s/tau) = exp2(acc);
// -2*s = -ln2 * acc.  48 blocks x 256 threads = 12288 rows exactly.
__global__ void finalize1_kernel(const float* __restrict__ Rlow,
                                 const float* __restrict__ Rhigh,
                                 const float* __restrict__ Dsame,
                                 const float* __restrict__ Dcross,
                                 float* __restrict__ partial) {
  __shared__ float red[256];
  int k = blockIdx.x * 256 + threadIdx.x;
  float d1 = Rlow[k] + Rhigh[k] - EXP2F(Dsame[k]);
  float d2 = Rhigh[NROWS + k] + Rlow[NROWS + k] - EXP2F(Dsame[NROWS + k]);
  float acc = 0.5f * (logf(d1) + logf(d2)) - LN2F * Dcross[k];
  red[threadIdx.x] = acc;
  __syncthreads();
  for (int s = 128; s > 0; s >>= 1) {
    if (threadIdx.x < s) red[threadIdx.x] += red[threadIdx.x + s];
    __syncthreads();
  }
  if (threadIdx.x == 0) partial[blockIdx.x] = red[0];
}

__global__ void finalize2_kernel(const float* __restrict__ partial,
                                 float* __restrict__ out) {
  float x = (threadIdx.x < FB) ? partial[threadIdx.x] : 0.f;
#pragma unroll
  for (int s = 32; s > 0; s >>= 1) x += __shfl_down(x, s, 64);
  if (threadIdx.x == 0) out[0] = x / (float)NROWS;
}

// ---------------------------------------------------------------------------
extern "C" void kernel_launch(void* const* d_in, const int* in_sizes, int n_in,
                              void* d_out, int out_size, void* d_ws,
                              size_t ws_size, hipStream_t stream) {
  const float* z1 = (const float*)d_in[0];
  const float* z2 = (const float*)d_in[1];
  const float* W1 = (const float*)d_in[2];
  const float* b1 = (const float*)d_in[3];
  const float* W2 = (const float*)d_in[4];
  const float* b2 = (const float*)d_in[5];
  float* out = (float*)d_out;

  char* ws = (char*)d_ws;
  size_t off = 0;
  auto alloc = [&](size_t bytes) -> void* {
    void* p = ws + off;
    off += (bytes + 255) & ~(size_t)255;
    return p;
  };
  __bf16* Zb   = (__bf16*)alloc((size_t)TWO_N * KDIM * 2); // reused as Nq
  __bf16* W1b  = (__bf16*)alloc((size_t)KDIM * KDIM * 2);
  __bf16* W2b  = (__bf16*)alloc((size_t)KDIM * KDIM * 2);
  __bf16* Tb   = (__bf16*)alloc((size_t)TWO_N * KDIM * 2);
  float*  H    = (float*)alloc((size_t)TWO_N * KDIM * 4);
  float*  SS   = (float*)alloc((size_t)TWO_N * 4);
  float*  Rlow = (float*)alloc((size_t)TWO_N * 4);
  float*  Rhigh= (float*)alloc((size_t)TWO_N * 4);
  float*  Dsame= (float*)alloc((size_t)TWO_N * 4);
  float*  Dcross=(float*)alloc((size_t)NROWS * 4);
  float*  partial=(float*)alloc((size_t)FB * 4);
  uchar*  Nq = (uchar*)Zb;  // Zb dead after proj1; fp8 fits in its footprint

  hipMemsetAsync(SS, 0, (size_t)TWO_N * 4, stream);
  hipMemsetAsync(Rlow, 0, (size_t)TWO_N * 4, stream);
  hipMemsetAsync(Rhigh, 0, (size_t)TWO_N * 4, stream);

  int n4z = NROWS * KDIM / 4;   // 786432
  int n4w = KDIM * KDIM / 4;    // 16384
  int n4all = 2 * n4z + 2 * n4w;
  cast_all_kernel<<<(n4all + 255) / 256, 256, 0, stream>>>(z1, z2, W1, W2, Zb,
                                                           W1b, W2b);

  proj1_kernel<<<dim3(TWO_N / BM, KDIM / BN), 256, 0, stream>>>(Zb, W1b, b1, Tb);
  proj2_kernel<<<dim3(TWO_N / BM, KDIM / BN), 256, 0, stream>>>(Tb, W2b, b2, H, SS);

  int n8n = TWO_N * KDIM / 8;   // 786432
  norm_kernel<<<(n8n + 255) / 256, 256, 0, stream>>>(H, SS, Nq);

  sim_kernel<<<(TWO_N / BM) * NCHUNK, 256, 0, stream>>>(Nq, Rlow, Rhigh,
                                                        Dsame, Dcross);
  finalize1_kernel<<<FB, 256, 0, stream>>>(Rlow, Rhigh, Dsame, Dcross, partial);
  finalize2_kernel<<<1, 64, 0, stream>>>(partial, out);
}

// Round 5
// 259.561 us; speedup vs baseline: 1.7338x; 1.0207x over previous
//
#include <hip/hip_runtime.h>
#include <hip/hip_bf16.h>
#include <hip/hip_fp8.h>

// ---------------------------------------------------------------------------
// GRACE contrastive loss, MI355X.
//  out = mean_k 0.5*(ln d1_k + ln d2_k) - 2*s12[k,k]
// With M=[n1;n2] (24576x256) everything is row sums of exp(M M^T / tau)
// split by j-half, plus diagonal probes.
//
// R11: force the MFMA:exp interleave with sched_group_barrier. Cross-round
// invariant: dur = 66us(matrix) + ~78us(VALU) + ~30us stall in EVERY
// geometry (R6/R8/R10) -> the pipes never overlap. R10's source-level
// ping-pong produced counters identical to R6's dependent version =>
// the compiler re-clustered (sank the independent exps after the MFMA
// cluster; they're dependency-free either way, so it has no reason to
// interleave). Fix: per nj, sched_group_barrier pattern
//   4x DS_READ -> 16 VALU -> 8 x { 1 MFMA, 6 VALU }
// so each ~34cy MFMA shadow carries 2 exps + 2 adds + overhead.
// Everything else byte-identical to R10 (no-spill geometry: BM=128,
// BJ=128, 2x2 wave grid, 2x32KB LDS, launch_bounds(256,2), grid 1536).
// ---------------------------------------------------------------------------

#define NROWS 12288
#define TWO_N 24576
#define KDIM 256
#define BM 128
#define BN 128
#define BK 32
#define BJ 128
#define NCHUNK 8
#define JCHUNK (TWO_N / NCHUNK) /* 3072 */
#define JTILES (JCHUNK / BJ)    /* 24 */
#define FB 48                   /* finalize partial blocks */
#define LOG2E 1.4426950408889634f
#define SIMSCALE 1.6986436f     /* sqrt(2*log2(e)); acc = (1/tau)*log2e*s */
#define LN2F 0.6931471805599453f

#if __has_builtin(__builtin_amdgcn_exp2f)
#define EXP2F(x) __builtin_amdgcn_exp2f(x)
#else
#define EXP2F(x) exp2f(x)
#endif

// sched_group_barrier masks (LLVM SchedGroupMask, per m137):
//   VALU=0x2  MFMA=0x8  DS_READ=0x100
#define SGB(mask, n) __builtin_amdgcn_sched_group_barrier((mask), (n), 0)

typedef __bf16 bf16x8 __attribute__((ext_vector_type(8)));
typedef __bf16 bf16x4v __attribute__((ext_vector_type(4)));
typedef float f32x4 __attribute__((ext_vector_type(4)));
typedef int i32x4 __attribute__((ext_vector_type(4)));
typedef int i32x8 __attribute__((ext_vector_type(8)));
typedef unsigned char uchar;

typedef const __attribute__((address_space(1))) void* gptr_t;
typedef __attribute__((address_space(3))) void* lptr_t;

// ======== legacy 128x128 bf16 GEMM core (proj1/proj2 only) ================
__device__ __forceinline__ void stage_slab(const __bf16* g, int row0, int kelem,
                                           __bf16* lds, int w, int l) {
#pragma unroll
  for (int t = 0; t < 2; ++t) {
    int chunk = w * 2 + t;
    int r = chunk * 16 + (l >> 2);
    int c = l & 3;
    int src = c ^ (r & 3);
    const __bf16* ga = g + (size_t)(row0 + r) * KDIM + kelem + src * 8;
    __bf16* la = lds + chunk * 512;
    __builtin_amdgcn_global_load_lds((gptr_t)ga, (lptr_t)la, 16, 0, 0);
  }
}

__device__ __forceinline__ bf16x8 read_frag(const __bf16* lds, int rowbase,
                                            int tile, int l) {
  int r = rowbase + tile * 16 + (l & 15);
  int q = l >> 4;
  int blk = q ^ (r & 3);
  return *(const bf16x8*)(lds + r * 32 + blk * 8);
}

__device__ __forceinline__ void gemm_tile_core(const __bf16* A, int arow0,
                                               const __bf16* B, int brow0,
                                               __bf16* As, __bf16* Bs,
                                               f32x4 (&acc)[4][4], int w, int l) {
  const int warow = (w >> 1) * 64;
  const int wbrow = (w & 1) * 64;
#pragma unroll
  for (int ks = 0; ks < KDIM / BK; ++ks) {
    __syncthreads();
    stage_slab(A, arow0, ks * BK, As, w, l);
    stage_slab(B, brow0, ks * BK, Bs, w, l);
    __syncthreads();
    bf16x8 aF[4], bF[4];
#pragma unroll
    for (int mi = 0; mi < 4; ++mi) aF[mi] = read_frag(As, warow, mi, l);
#pragma unroll
    for (int ni = 0; ni < 4; ++ni) bF[ni] = read_frag(Bs, wbrow, ni, l);
#pragma unroll
    for (int mi = 0; mi < 4; ++mi)
#pragma unroll
      for (int ni = 0; ni < 4; ++ni)
        acc[mi][ni] = __builtin_amdgcn_mfma_f32_16x16x32_bf16(
            aF[mi], bF[ni], acc[mi][ni], 0, 0, 0);
  }
}

// ---------------------------------------------------------------------------
// one launch: cast z1, z2, W1, W2 to bf16 (float4 granules)
__global__ void cast_all_kernel(const float* __restrict__ z1,
                                const float* __restrict__ z2,
                                const float* __restrict__ W1,
                                const float* __restrict__ W2,
                                __bf16* __restrict__ Zb,
                                __bf16* __restrict__ W1b,
                                __bf16* __restrict__ W2b) {
  const int n4z = NROWS * KDIM / 4;  // 786432
  const int n4w = KDIM * KDIM / 4;   // 16384
  int i = blockIdx.x * blockDim.x + threadIdx.x;
  const float* src;
  __bf16* dst;
  int j;
  if (i < n4z) {
    src = z1; dst = Zb; j = i;
  } else if (i < 2 * n4z) {
    src = z2; dst = Zb + (size_t)NROWS * KDIM; j = i - n4z;
  } else if (i < 2 * n4z + n4w) {
    src = W1; dst = W1b; j = i - 2 * n4z;
  } else if (i < 2 * n4z + 2 * n4w) {
    src = W2; dst = W2b; j = i - 2 * n4z - n4w;
  } else {
    return;
  }
  float4 v = *(const float4*)(src + (size_t)j * 4);
  bf16x4v o;
  o[0] = (__bf16)v.x; o[1] = (__bf16)v.y; o[2] = (__bf16)v.z; o[3] = (__bf16)v.w;
  *(bf16x4v*)(dst + (size_t)j * 4) = o;
}

// T = ELU(Z @ W1^T + b1), stored bf16
__global__ __launch_bounds__(256, 2) void proj1_kernel(
    const __bf16* __restrict__ Zb, const __bf16* __restrict__ W1b,
    const float* __restrict__ b1, __bf16* __restrict__ Tb) {
  __shared__ __align__(16) __bf16 As[BM * BK];
  __shared__ __align__(16) __bf16 Bs[BN * BK];
  int w = threadIdx.x >> 6, l = threadIdx.x & 63;
  int i0 = blockIdx.x * BM, j0 = blockIdx.y * BN;
  int warow = (w >> 1) * 64, wbrow = (w & 1) * 64;
  f32x4 acc[4][4] = {};
  gemm_tile_core(Zb, i0, W1b, j0, As, Bs, acc, w, l);
  float bias[4];
#pragma unroll
  for (int ni = 0; ni < 4; ++ni) bias[ni] = b1[j0 + wbrow + ni * 16 + (l & 15)];
#pragma unroll
  for (int mi = 0; mi < 4; ++mi)
#pragma unroll
    for (int ni = 0; ni < 4; ++ni)
#pragma unroll
      for (int v = 0; v < 4; ++v) {
        int row = i0 + warow + mi * 16 + (l >> 4) * 4 + v;
        int col = j0 + wbrow + ni * 16 + (l & 15);
        float x = acc[mi][ni][v] + bias[ni];
        x = x > 0.f ? x : (EXP2F(x * LOG2E) - 1.f);  // ELU
        Tb[(size_t)row * KDIM + col] = (__bf16)x;
      }
}

// H = T @ W2^T + b2 (fp32), plus per-row sum of squares via atomics
__global__ __launch_bounds__(256, 2) void proj2_kernel(
    const __bf16* __restrict__ Tb, const __bf16* __restrict__ W2b,
    const float* __restrict__ b2, float* __restrict__ H,
    float* __restrict__ SS) {
  __shared__ __align__(16) __bf16 As[BM * BK];
  __shared__ __align__(16) __bf16 Bs[BN * BK];
  int w = threadIdx.x >> 6, l = threadIdx.x & 63;
  int i0 = blockIdx.x * BM, j0 = blockIdx.y * BN;
  int warow = (w >> 1) * 64, wbrow = (w & 1) * 64;
  f32x4 acc[4][4] = {};
  gemm_tile_core(Tb, i0, W2b, j0, As, Bs, acc, w, l);
  float bias[4];
#pragma unroll
  for (int ni = 0; ni < 4; ++ni) bias[ni] = b2[j0 + wbrow + ni * 16 + (l & 15)];
  float ss[4][4] = {};
#pragma unroll
  for (int mi = 0; mi < 4; ++mi)
#pragma unroll
    for (int ni = 0; ni < 4; ++ni)
#pragma unroll
      for (int v = 0; v < 4; ++v) {
        int row = i0 + warow + mi * 16 + (l >> 4) * 4 + v;
        int col = j0 + wbrow + ni * 16 + (l & 15);
        float x = acc[mi][ni][v] + bias[ni];
        H[(size_t)row * KDIM + col] = x;
        ss[mi][v] += x * x;
      }
#pragma unroll
  for (int mi = 0; mi < 4; ++mi)
#pragma unroll
    for (int v = 0; v < 4; ++v) {
      float x = ss[mi][v];
      x += __shfl_xor(x, 1, 64);
      x += __shfl_xor(x, 2, 64);
      x += __shfl_xor(x, 4, 64);
      x += __shfl_xor(x, 8, 64);
      if ((l & 15) == 0)
        atomicAdd(&SS[i0 + warow + mi * 16 + (l >> 4) * 4 + v], x);
    }
}

// pack 4 floats -> 4 fp8 e4m3 bytes
__device__ __forceinline__ unsigned int pack4_fp8(float a, float b, float c,
                                                  float d) {
#if __has_builtin(__builtin_amdgcn_cvt_pk_fp8_f32)
  int v = 0;
  v = __builtin_amdgcn_cvt_pk_fp8_f32(a, b, v, false);
  v = __builtin_amdgcn_cvt_pk_fp8_f32(c, d, v, true);
  return (unsigned int)v;
#else
  __hip_fp8_e4m3 qa(a), qb(b), qc(c), qd(d);
  return (unsigned int)qa.__x | ((unsigned int)qb.__x << 8) |
         ((unsigned int)qc.__x << 16) | ((unsigned int)qd.__x << 24);
#endif
}

// Nq = fp8(H * rsqrt(SS[row]) * SIMSCALE) — 8 elements per thread.
// SIMSCALE folds the (1/tau)*log2(e) exponent scale into the data:
// dot(Nq_i, Nq_j) = 2.8854 * cos_ij, so exp2(acc) = exp(cos/tau).
__global__ void norm_kernel(const float* __restrict__ H,
                            const float* __restrict__ SS,
                            uchar* __restrict__ Nq) {
  int i = blockIdx.x * blockDim.x + threadIdx.x;
  size_t idx = (size_t)i * 8;
  if (idx >= (size_t)TWO_N * KDIM) return;
  int row = (int)(idx >> 8);
  float inv = rsqrtf(SS[row]) * SIMSCALE;
  float4 h0 = *(const float4*)(H + idx);
  float4 h1 = *(const float4*)(H + idx + 4);
  uint2 o;
  o.x = pack4_fp8(h0.x * inv, h0.y * inv, h0.z * inv, h0.w * inv);
  o.y = pack4_fp8(h1.x * inv, h1.y * inv, h1.z * inv, h1.w * inv);
  *(uint2*)(Nq + idx) = o;
}

// ======== R11 sim kernel: R10 + sched_group_barrier interleave =============
// grid = 1536 1D blocks (2/CU resident, 3 exact rounds). chunk = blockIdx&7
// (XCD-pinned j-range), itile = blockIdx>>3 (128 A-rows). 2x2 wave grid,
// 64 rows x 64 cols per wave. LDS 2x32KB double buffer, one barrier per jt.
// launch_bounds(256,2): no spill (VGPR 112 in R10).
// Per nj: 8 MFMAs -> acc[nj&1]; 16 exp2s of acc[(nj&1)^1]; the SGB pattern
// pins the emission to 4xDS_READ, 16 VALU, then 8 x {1 MFMA, 6 VALU} so
// the trans/VALU work issues inside each MFMA's ~34cy shadow.
__global__ __launch_bounds__(256, 2) void sim_kernel(
    const uchar* __restrict__ Nq, float* __restrict__ Rlow,
    float* __restrict__ Rhigh, float* __restrict__ Dsame,
    float* __restrict__ Dcross) {
  __shared__ __align__(16) uchar Bs[2][BJ * KDIM];  // 2 x 32KB
  int tid = threadIdx.x;
  int w = tid >> 6, l = tid & 63;
  int q = l >> 4;
  int b = blockIdx.x;
  int chunk = b & 7;           // XCD id under round-robin dispatch
  int i0 = (b >> 3) * BM;
  int jbase = chunk * JCHUNK;
  int warow = (w >> 1) * 64;   // A rows of this wave
  int wbcol = (w & 1) * 64;    // B cols of this wave

  // per-lane constant staging offsets (source-side XOR swizzle: LDS slot c
  // of row r holds global 16B-block c ^ (r&15)); jt advances by 32KB.
  unsigned off0[8];
#pragma unroll
  for (int t = 0; t < 8; ++t) {
    int ch = w * 8 + t;            // wave-uniform chunk 0..31 (1KB each)
    int r = ch * 4 + (l >> 4);     // row 0..127 (4 rows per chunk)
    int c = l & 15;                // dest 16B-block slot
    int src = c ^ (r & 15);        // global k-block landing in slot c
    off0[t] = (unsigned)((jbase + r) * KDIM + src * 16);
  }
  auto stage = [&](int jt, int bi) {
    unsigned jo = (unsigned)(jt * (BJ * KDIM));
#pragma unroll
    for (int t = 0; t < 8; ++t) {
      const uchar* ga = Nq + (size_t)(off0[t] + jo);
      uchar* la = Bs[bi] + (w * 8 + t) * 1024;  // wave-uniform base
      __builtin_amdgcn_global_load_lds((gptr_t)ga, (lptr_t)la, 16, 0, 0);
    }
  };

  // ---- A fragments in registers: aF[mi][hf], 8 x i32x8 = 64 VGPRs ----
  // f8f6f4 16x16x128 A layout: lane holds row (l&15), k = q*32 + 0..31.
  i32x8 aF[4][2];
#pragma unroll
  for (int mi = 0; mi < 4; ++mi) {
    const uchar* ap =
        Nq + (size_t)(i0 + warow + mi * 16 + (l & 15)) * KDIM + q * 32;
#pragma unroll
    for (int hf = 0; hf < 2; ++hf)
      aF[mi][hf] = *(const i32x8*)(ap + hf * 128);
  }

  float rs[4][4] = {};  // running row sums (per mi, per v)

  // ping-pong accumulators; acc[1] seeded so the first deferred exp adds 0
  f32x4 acc[2][4];
#pragma unroll
  for (int mi = 0; mi < 4; ++mi)
    acc[1][mi] = (f32x4){-3.0e38f, -3.0e38f, -3.0e38f, -3.0e38f};

  stage(0, 0);  // prologue

  for (int jt = 0; jt < JTILES; ++jt) {
    int bi = jt & 1;
    __syncthreads();                       // stage(jt) done; prev readers done
    if (jt + 1 < JTILES) stage(jt + 1, bi ^ 1);  // drains at NEXT barrier

    int j0 = jbase + jt * BJ;
    bool dsame = (j0 == i0);
    bool dcross = (j0 == i0 + NROWS);

#pragma unroll
    for (int nj = 0; nj < 4; ++nj) {
      const int cur = nj & 1, prv = cur ^ 1;
      int row = wbcol + nj * 16 + (l & 15);
      int rx = row & 15;
      const uchar* base = Bs[bi] + row * KDIM;
      // B fragments for both K-halves up front
      i32x8 bF[2];
#pragma unroll
      for (int hf = 0; hf < 2; ++hf) {
        int kb = hf * 8 + 2 * q;                 // even global block index
        i32x4 lo = *(const i32x4*)(base + ((kb ^ rx) << 4));
        i32x4 hi = *(const i32x4*)(base + (((kb + 1) ^ rx) << 4));
        bF[hf] = __builtin_shufflevector(lo, hi, 0, 1, 2, 3, 4, 5, 6, 7);
      }
#pragma unroll
      for (int mi = 0; mi < 4; ++mi)
        acc[cur][mi] = (f32x4){0.f, 0.f, 0.f, 0.f};
      // 8 MFMAs into acc[cur]; 16 exps of acc[prv] interleaved 1:2 so the
      // trans/VALU work issues while the matrix pipe is busy.
#pragma unroll
      for (int hf = 0; hf < 2; ++hf)
#pragma unroll
        for (int mi = 0; mi < 4; ++mi) {
          acc[cur][mi] = __builtin_amdgcn_mfma_scale_f32_16x16x128_f8f6f4(
              aF[mi][hf], bF[hf], acc[cur][mi], 0, 0, 0, 0x7F7F7F7F, 0,
              0x7F7F7F7F);
          const int e0 = (hf * 4 + mi) * 2, e1 = e0 + 1;
          rs[e0 >> 2][e0 & 3] += EXP2F(acc[prv][e0 >> 2][e0 & 3]);
          rs[e1 >> 2][e1 & 3] += EXP2F(acc[prv][e1 >> 2][e1 & 3]);
        }

      // ---- pin the schedule for this nj: the compiler otherwise clusters
      // the MFMAs and sinks the (independent) exps below them, serializing
      // the matrix and VALU phases (R6 == R10 counters). Pattern:
      // 4x ds_read (bF), 16 VALU (zero-init/addr), 8 x {1 MFMA, 6 VALU}.
      SGB(0x100, 4);
      SGB(0x2, 16);
#pragma unroll
      for (int s = 0; s < 8; ++s) {
        SGB(0x8, 1);
        SGB(0x2, 6);
      }

      if (dsame | dcross) {       // wave-uniform, 2 of 24 jt iterations
        float* D = dsame ? Dsame : Dcross;
#pragma unroll
        for (int mi = 0; mi < 4; ++mi)
#pragma unroll
          for (int v = 0; v < 4; ++v) {
            int li = warow + mi * 16 + q * 4 + v;
            int lj = wbcol + nj * 16 + (l & 15);
            if (li == lj) D[i0 + li] = acc[cur][mi][v];
          }
      }
    }
  }

  // flush the last nj's accumulator (nj=3 wrote acc[1])
#pragma unroll
  for (int mi = 0; mi < 4; ++mi)
#pragma unroll
    for (int v = 0; v < 4; ++v)
      rs[mi][v] += EXP2F(acc[1][mi][v]);

  // cross-lane (16-wide) reduce, one atomicAdd per row per wave
  float* R = (chunk >= NCHUNK / 2) ? Rhigh : Rlow;
#pragma unroll
  for (int mi = 0; mi < 4; ++mi)
#pragma unroll
    for (int v = 0; v < 4; ++v) {
      float x = rs[mi][v];
      x += __shfl_xor(x, 1, 64);
      x += __shfl_xor(x, 2, 64);
      x += __shfl_xor(x, 4, 64);
      x += __shfl_xor(x, 8, 64);
      if ((l & 15) == 0)
        atomicAdd(&R[i0 + warow + mi * 16 + q * 4 + v], x);
    }
}

// Dsame/Dcross hold acc = (1/tau)*log2e * s. exp(s/tau) = exp2(acc);
// -2*s = -ln2 * acc.  48 blocks x 256 threads = 12288 rows exactly.
__global__ void finalize1_kernel(const float* __restrict__ Rlow,
                                 const float* __restrict__ Rhigh,
                                 const float* __restrict__ Dsame,
                                 const float* __restrict__ Dcross,
                                 float* __restrict__ partial) {
  __shared__ float red[256];
  int k = blockIdx.x * 256 + threadIdx.x;
  float d1 = Rlow[k] + Rhigh[k] - EXP2F(Dsame[k]);
  float d2 = Rhigh[NROWS + k] + Rlow[NROWS + k] - EXP2F(Dsame[NROWS + k]);
  float acc = 0.5f * (logf(d1) + logf(d2)) - LN2F * Dcross[k];
  red[threadIdx.x] = acc;
  __syncthreads();
  for (int s = 128; s > 0; s >>= 1) {
    if (threadIdx.x < s) red[threadIdx.x] += red[threadIdx.x + s];
    __syncthreads();
  }
  if (threadIdx.x == 0) partial[blockIdx.x] = red[0];
}

__global__ void finalize2_kernel(const float* __restrict__ partial,
                                 float* __restrict__ out) {
  float x = (threadIdx.x < FB) ? partial[threadIdx.x] : 0.f;
#pragma unroll
  for (int s = 32; s > 0; s >>= 1) x += __shfl_down(x, s, 64);
  if (threadIdx.x == 0) out[0] = x / (float)NROWS;
}

// ---------------------------------------------------------------------------
extern "C" void kernel_launch(void* const* d_in, const int* in_sizes, int n_in,
                              void* d_out, int out_size, void* d_ws,
                              size_t ws_size, hipStream_t stream) {
  const float* z1 = (const float*)d_in[0];
  const float* z2 = (const float*)d_in[1];
  const float* W1 = (const float*)d_in[2];
  const float* b1 = (const float*)d_in[3];
  const float* W2 = (const float*)d_in[4];
  const float* b2 = (const float*)d_in[5];
  float* out = (float*)d_out;

  char* ws = (char*)d_ws;
  size_t off = 0;
  auto alloc = [&](size_t bytes) -> void* {
    void* p = ws + off;
    off += (bytes + 255) & ~(size_t)255;
    return p;
  };
  __bf16* Zb   = (__bf16*)alloc((size_t)TWO_N * KDIM * 2); // reused as Nq
  __bf16* W1b  = (__bf16*)alloc((size_t)KDIM * KDIM * 2);
  __bf16* W2b  = (__bf16*)alloc((size_t)KDIM * KDIM * 2);
  __bf16* Tb   = (__bf16*)alloc((size_t)TWO_N * KDIM * 2);
  float*  H    = (float*)alloc((size_t)TWO_N * KDIM * 4);
  float*  SS   = (float*)alloc((size_t)TWO_N * 4);
  float*  Rlow = (float*)alloc((size_t)TWO_N * 4);
  float*  Rhigh= (float*)alloc((size_t)TWO_N * 4);
  float*  Dsame= (float*)alloc((size_t)TWO_N * 4);
  float*  Dcross=(float*)alloc((size_t)NROWS * 4);
  float*  partial=(float*)alloc((size_t)FB * 4);
  uchar*  Nq = (uchar*)Zb;  // Zb dead after proj1; fp8 fits in its footprint

  hipMemsetAsync(SS, 0, (size_t)TWO_N * 4, stream);
  hipMemsetAsync(Rlow, 0, (size_t)TWO_N * 4, stream);
  hipMemsetAsync(Rhigh, 0, (size_t)TWO_N * 4, stream);

  int n4z = NROWS * KDIM / 4;   // 786432
  int n4w = KDIM * KDIM / 4;    // 16384
  int n4all = 2 * n4z + 2 * n4w;
  cast_all_kernel<<<(n4all + 255) / 256, 256, 0, stream>>>(z1, z2, W1, W2, Zb,
                                                           W1b, W2b);

  proj1_kernel<<<dim3(TWO_N / BM, KDIM / BN), 256, 0, stream>>>(Zb, W1b, b1, Tb);
  proj2_kernel<<<dim3(TWO_N / BM, KDIM / BN), 256, 0, stream>>>(Tb, W2b, b2, H, SS);

  int n8n = TWO_N * KDIM / 8;   // 786432
  norm_kernel<<<(n8n + 255) / 256, 256, 0, stream>>>(H, SS, Nq);

  sim_kernel<<<(TWO_N / BM) * NCHUNK, 256, 0, stream>>>(Nq, Rlow, Rhigh,
                                                        Dsame, Dcross);
  finalize1_kernel<<<FB, 256, 0, stream>>>(Rlow, Rhigh, Dsame, Dcross, partial);
  finalize2_kernel<<<1, 64, 0, stream>>>(partial, out);
}

// Round 6
// 237.869 us; speedup vs baseline: 1.8919x; 1.0912x over previous
//
#include <hip/hip_runtime.h>
#include <hip/hip_bf16.h>
#include <hip/hip_fp8.h>

// ---------------------------------------------------------------------------
// GRACE contrastive loss, MI355X.
//  out = mean_k 0.5*(ln d1_k + ln d2_k) - 2*s12[k,k]
// With M=[n1;n2] (24576x256) everything is row sums of exp(M M^T / tau)
// split by j-half, plus diagonal probes.
//
// R12: SYMMETRY HALVING. Four structural nulls (R8 occupancy, R10 acc
// ping-pong, R11 sched_group_barrier) replicate the known ~36-39% ceiling
// of the 2-barrier-per-K-step loop: per SIMD per nj-step, 716cy =
// 277 matrix + 333 VALU + 106 idle, immovable by scheduling. So cut the
// work: S = exp2(D) is SYMMETRIC -> compute only upper-triangle 128x128
// tiles (18528 of 36864 = 50.3%). Each off-diag tile feeds row-sums
// (rows of I, as before) AND col-sums (rows of J): 15-add in-lane tree
// + shfl_xor(16,32) + one 16-lane atomicAdd per nj. Diagonal tiles are
// computed whole, row-sums only (no double count).
// Load balance: pair row-tiles (I, 191-I) -> constant 193 J-tiles/pair;
// 96 pairs x 16 slots = grid 1536 (12-13 tiles each), same 2-blocks/CU,
// same LDS/staging/XOR-swizzle as R10. rs flushes at half(J)-crossing /
// A-switch (<=3/block + final); aF reloads once at segment switch.
// ---------------------------------------------------------------------------

#define NROWS 12288
#define TWO_N 24576
#define KDIM 256
#define BM 128
#define BN 128
#define BK 32
#define BJ 128
#define NTILE 192   /* 24576 / 128 row-tiles */
#define PAIRS 96
#define SLOTS 16
#define FB 48                   /* finalize partial blocks */
#define LOG2E 1.4426950408889634f
#define SIMSCALE 1.6986436f     /* sqrt(2*log2(e)); acc = (1/tau)*log2e*s */
#define LN2F 0.6931471805599453f

#if __has_builtin(__builtin_amdgcn_exp2f)
#define EXP2F(x) __builtin_amdgcn_exp2f(x)
#else
#define EXP2F(x) exp2f(x)
#endif

typedef __bf16 bf16x8 __attribute__((ext_vector_type(8)));
typedef __bf16 bf16x4v __attribute__((ext_vector_type(4)));
typedef float f32x4 __attribute__((ext_vector_type(4)));
typedef int i32x4 __attribute__((ext_vector_type(4)));
typedef int i32x8 __attribute__((ext_vector_type(8)));
typedef unsigned char uchar;

typedef const __attribute__((address_space(1))) void* gptr_t;
typedef __attribute__((address_space(3))) void* lptr_t;

// ======== legacy 128x128 bf16 GEMM core (proj1/proj2 only) ================
__device__ __forceinline__ void stage_slab(const __bf16* g, int row0, int kelem,
                                           __bf16* lds, int w, int l) {
#pragma unroll
  for (int t = 0; t < 2; ++t) {
    int chunk = w * 2 + t;
    int r = chunk * 16 + (l >> 2);
    int c = l & 3;
    int src = c ^ (r & 3);
    const __bf16* ga = g + (size_t)(row0 + r) * KDIM + kelem + src * 8;
    __bf16* la = lds + chunk * 512;
    __builtin_amdgcn_global_load_lds((gptr_t)ga, (lptr_t)la, 16, 0, 0);
  }
}

__device__ __forceinline__ bf16x8 read_frag(const __bf16* lds, int rowbase,
                                            int tile, int l) {
  int r = rowbase + tile * 16 + (l & 15);
  int q = l >> 4;
  int blk = q ^ (r & 3);
  return *(const bf16x8*)(lds + r * 32 + blk * 8);
}

__device__ __forceinline__ void gemm_tile_core(const __bf16* A, int arow0,
                                               const __bf16* B, int brow0,
                                               __bf16* As, __bf16* Bs,
                                               f32x4 (&acc)[4][4], int w, int l) {
  const int warow = (w >> 1) * 64;
  const int wbrow = (w & 1) * 64;
#pragma unroll
  for (int ks = 0; ks < KDIM / BK; ++ks) {
    __syncthreads();
    stage_slab(A, arow0, ks * BK, As, w, l);
    stage_slab(B, brow0, ks * BK, Bs, w, l);
    __syncthreads();
    bf16x8 aF[4], bF[4];
#pragma unroll
    for (int mi = 0; mi < 4; ++mi) aF[mi] = read_frag(As, warow, mi, l);
#pragma unroll
    for (int ni = 0; ni < 4; ++ni) bF[ni] = read_frag(Bs, wbrow, ni, l);
#pragma unroll
    for (int mi = 0; mi < 4; ++mi)
#pragma unroll
      for (int ni = 0; ni < 4; ++ni)
        acc[mi][ni] = __builtin_amdgcn_mfma_f32_16x16x32_bf16(
            aF[mi], bF[ni], acc[mi][ni], 0, 0, 0);
  }
}

// ---------------------------------------------------------------------------
// one launch: cast z1, z2, W1, W2 to bf16 (float4 granules)
__global__ void cast_all_kernel(const float* __restrict__ z1,
                                const float* __restrict__ z2,
                                const float* __restrict__ W1,
                                const float* __restrict__ W2,
                                __bf16* __restrict__ Zb,
                                __bf16* __restrict__ W1b,
                                __bf16* __restrict__ W2b) {
  const int n4z = NROWS * KDIM / 4;  // 786432
  const int n4w = KDIM * KDIM / 4;   // 16384
  int i = blockIdx.x * blockDim.x + threadIdx.x;
  const float* src;
  __bf16* dst;
  int j;
  if (i < n4z) {
    src = z1; dst = Zb; j = i;
  } else if (i < 2 * n4z) {
    src = z2; dst = Zb + (size_t)NROWS * KDIM; j = i - n4z;
  } else if (i < 2 * n4z + n4w) {
    src = W1; dst = W1b; j = i - 2 * n4z;
  } else if (i < 2 * n4z + 2 * n4w) {
    src = W2; dst = W2b; j = i - 2 * n4z - n4w;
  } else {
    return;
  }
  float4 v = *(const float4*)(src + (size_t)j * 4);
  bf16x4v o;
  o[0] = (__bf16)v.x; o[1] = (__bf16)v.y; o[2] = (__bf16)v.z; o[3] = (__bf16)v.w;
  *(bf16x4v*)(dst + (size_t)j * 4) = o;
}

// T = ELU(Z @ W1^T + b1), stored bf16
__global__ __launch_bounds__(256, 2) void proj1_kernel(
    const __bf16* __restrict__ Zb, const __bf16* __restrict__ W1b,
    const float* __restrict__ b1, __bf16* __restrict__ Tb) {
  __shared__ __align__(16) __bf16 As[BM * BK];
  __shared__ __align__(16) __bf16 Bs[BN * BK];
  int w = threadIdx.x >> 6, l = threadIdx.x & 63;
  int i0 = blockIdx.x * BM, j0 = blockIdx.y * BN;
  int warow = (w >> 1) * 64, wbrow = (w & 1) * 64;
  f32x4 acc[4][4] = {};
  gemm_tile_core(Zb, i0, W1b, j0, As, Bs, acc, w, l);
  float bias[4];
#pragma unroll
  for (int ni = 0; ni < 4; ++ni) bias[ni] = b1[j0 + wbrow + ni * 16 + (l & 15)];
#pragma unroll
  for (int mi = 0; mi < 4; ++mi)
#pragma unroll
    for (int ni = 0; ni < 4; ++ni)
#pragma unroll
      for (int v = 0; v < 4; ++v) {
        int row = i0 + warow + mi * 16 + (l >> 4) * 4 + v;
        int col = j0 + wbrow + ni * 16 + (l & 15);
        float x = acc[mi][ni][v] + bias[ni];
        x = x > 0.f ? x : (EXP2F(x * LOG2E) - 1.f);  // ELU
        Tb[(size_t)row * KDIM + col] = (__bf16)x;
      }
}

// H = T @ W2^T + b2 (fp32), plus per-row sum of squares via atomics
__global__ __launch_bounds__(256, 2) void proj2_kernel(
    const __bf16* __restrict__ Tb, const __bf16* __restrict__ W2b,
    const float* __restrict__ b2, float* __restrict__ H,
    float* __restrict__ SS) {
  __shared__ __align__(16) __bf16 As[BM * BK];
  __shared__ __align__(16) __bf16 Bs[BN * BK];
  int w = threadIdx.x >> 6, l = threadIdx.x & 63;
  int i0 = blockIdx.x * BM, j0 = blockIdx.y * BN;
  int warow = (w >> 1) * 64, wbrow = (w & 1) * 64;
  f32x4 acc[4][4] = {};
  gemm_tile_core(Tb, i0, W2b, j0, As, Bs, acc, w, l);
  float bias[4];
#pragma unroll
  for (int ni = 0; ni < 4; ++ni) bias[ni] = b2[j0 + wbrow + ni * 16 + (l & 15)];
  float ss[4][4] = {};
#pragma unroll
  for (int mi = 0; mi < 4; ++mi)
#pragma unroll
    for (int ni = 0; ni < 4; ++ni)
#pragma unroll
      for (int v = 0; v < 4; ++v) {
        int row = i0 + warow + mi * 16 + (l >> 4) * 4 + v;
        int col = j0 + wbrow + ni * 16 + (l & 15);
        float x = acc[mi][ni][v] + bias[ni];
        H[(size_t)row * KDIM + col] = x;
        ss[mi][v] += x * x;
      }
#pragma unroll
  for (int mi = 0; mi < 4; ++mi)
#pragma unroll
    for (int v = 0; v < 4; ++v) {
      float x = ss[mi][v];
      x += __shfl_xor(x, 1, 64);
      x += __shfl_xor(x, 2, 64);
      x += __shfl_xor(x, 4, 64);
      x += __shfl_xor(x, 8, 64);
      if ((l & 15) == 0)
        atomicAdd(&SS[i0 + warow + mi * 16 + (l >> 4) * 4 + v], x);
    }
}

// pack 4 floats -> 4 fp8 e4m3 bytes
__device__ __forceinline__ unsigned int pack4_fp8(float a, float b, float c,
                                                  float d) {
#if __has_builtin(__builtin_amdgcn_cvt_pk_fp8_f32)
  int v = 0;
  v = __builtin_amdgcn_cvt_pk_fp8_f32(a, b, v, false);
  v = __builtin_amdgcn_cvt_pk_fp8_f32(c, d, v, true);
  return (unsigned int)v;
#else
  __hip_fp8_e4m3 qa(a), qb(b), qc(c), qd(d);
  return (unsigned int)qa.__x | ((unsigned int)qb.__x << 8) |
         ((unsigned int)qc.__x << 16) | ((unsigned int)qd.__x << 24);
#endif
}

// Nq = fp8(H * rsqrt(SS[row]) * SIMSCALE) — 8 elements per thread.
// SIMSCALE folds the (1/tau)*log2(e) exponent scale into the data:
// dot(Nq_i, Nq_j) = 2.8854 * cos_ij, so exp2(acc) = exp(cos/tau).
__global__ void norm_kernel(const float* __restrict__ H,
                            const float* __restrict__ SS,
                            uchar* __restrict__ Nq) {
  int i = blockIdx.x * blockDim.x + threadIdx.x;
  size_t idx = (size_t)i * 8;
  if (idx >= (size_t)TWO_N * KDIM) return;
  int row = (int)(idx >> 8);
  float inv = rsqrtf(SS[row]) * SIMSCALE;
  float4 h0 = *(const float4*)(H + idx);
  float4 h1 = *(const float4*)(H + idx + 4);
  uint2 o;
  o.x = pack4_fp8(h0.x * inv, h0.y * inv, h0.z * inv, h0.w * inv);
  o.y = pack4_fp8(h1.x * inv, h1.y * inv, h1.z * inv, h1.w * inv);
  *(uint2*)(Nq + idx) = o;
}

// ======== R12 sim kernel: upper-triangle tiles, row+col sums ===============
// Pair p = (I1=p, I2=191-p): flattened F in [0,193):
//   F <  L1=192-I1 : A-tile = I1, J-tile = I1 + F   (seg1, covers row I1)
//   F >= L1        : A-tile = I2, J-tile = F - 1    (seg2, covers row I2)
// A <= J always; F==0 and F==L1 are the two diagonal tiles.
// Per off-diag tile: row-sums -> rows of A, target R[half(J)];
//                    col-sums -> rows of J, target R[half(A)] (atomics).
// Diag tile: row-sums only (tile computed whole => complete, no doubling).
// grid = 96 pairs x 16 slots = 1536 blocks; slot 0: 13 tiles, else 12.
// Same 2x2 wave grid (64x64), 2x32KB LDS dbuf, XOR-swizzled staging,
// launch_bounds(256,2) (no spill).
__global__ __launch_bounds__(256, 2) void sim_kernel(
    const uchar* __restrict__ Nq, float* __restrict__ Rlow,
    float* __restrict__ Rhigh, float* __restrict__ Dsame,
    float* __restrict__ Dcross) {
  __shared__ __align__(16) uchar Bs[2][BJ * KDIM];  // 2 x 32KB
  int tid = threadIdx.x;
  int w = tid >> 6, l = tid & 63;
  int q = l >> 4;
  int b = blockIdx.x;
  int p = b >> 4;              // pair index 0..95
  int s = b & 15;              // slot within pair
  const int I1 = p, I2 = NTILE - 1 - p;
  const int L1 = NTILE - I1;   // seg1 length
  int fstart = (s == 0) ? 0 : 13 + (s - 1) * 12;
  int fend = fstart + ((s == 0) ? 13 : 12);
  int warow = (w >> 1) * 64;   // A rows of this wave
  int wbcol = (w & 1) * 64;    // B cols of this wave

  // per-lane staging offsets within a 128x256B tile (source-side XOR
  // swizzle: LDS slot c of row r holds global 16B-block c ^ (r&15)).
  unsigned off0[8];
#pragma unroll
  for (int t = 0; t < 8; ++t) {
    int ch = w * 8 + t;            // wave-uniform chunk 0..31 (1KB each)
    int r = ch * 4 + (l >> 4);     // row 0..127 (4 rows per chunk)
    int c = l & 15;                // dest 16B-block slot
    int src = c ^ (r & 15);        // global k-block landing in slot c
    off0[t] = (unsigned)(r * KDIM + src * 16);
  }
  auto jtile_of = [&](int F) { return (F < L1) ? (I1 + F) : (F - 1); };
  auto atile_of = [&](int F) { return (F < L1) ? I1 : I2; };

  auto stage = [&](int F, int bi) {
    unsigned jo = (unsigned)(jtile_of(F) * (BM * KDIM));
#pragma unroll
    for (int t = 0; t < 8; ++t) {
      const uchar* ga = Nq + (size_t)(jo + off0[t]);
      uchar* la = Bs[bi] + (w * 8 + t) * 1024;  // wave-uniform base
      __builtin_amdgcn_global_load_lds((gptr_t)ga, (lptr_t)la, 16, 0, 0);
    }
  };

  // ---- A fragments: aF[mi][hf], 8 x i32x8 = 64 VGPRs ----
  i32x8 aF[4][2];
  auto load_aF = [&](int Atile) {
#pragma unroll
    for (int mi = 0; mi < 4; ++mi) {
      const uchar* ap = Nq +
          (size_t)(Atile * BM + warow + mi * 16 + (l & 15)) * KDIM + q * 32;
#pragma unroll
      for (int hf = 0; hf < 2; ++hf)
        aF[mi][hf] = *(const i32x8*)(ap + hf * 128);
    }
  };

  float rs[4][4] = {};  // running row sums for current (A, half(J)) span

  auto flushrs = [&](int Atile, int h) {
    float* R = h ? Rhigh : Rlow;
#pragma unroll
    for (int mi = 0; mi < 4; ++mi)
#pragma unroll
      for (int v = 0; v < 4; ++v) {
        float x = rs[mi][v];
        x += __shfl_xor(x, 1, 64);
        x += __shfl_xor(x, 2, 64);
        x += __shfl_xor(x, 4, 64);
        x += __shfl_xor(x, 8, 64);
        if ((l & 15) == 0)
          atomicAdd(&R[Atile * BM + warow + mi * 16 + q * 4 + v], x);
        rs[mi][v] = 0.f;
      }
  };

  int Aprev = atile_of(fstart);
  int hprev = (jtile_of(fstart) >= NTILE / 2) ? 1 : 0;
  load_aF(Aprev);
  stage(fstart, 0);  // prologue

  for (int f = fstart; f < fend; ++f) {
    int bi = (f - fstart) & 1;
    __syncthreads();                       // stage(f) done; prev readers done
    if (f + 1 < fend) stage(f + 1, bi ^ 1);  // drains at NEXT barrier

    int Atile = atile_of(f);
    int Jt = jtile_of(f);
    int h = (Jt >= NTILE / 2) ? 1 : 0;
    if (Atile != Aprev) {          // segment switch (<=1 per block)
      flushrs(Aprev, hprev);
      load_aF(Atile);
      Aprev = Atile;
      hprev = h;
    } else if (h != hprev) {       // half(J) crossing (<=1 per segment)
      flushrs(Aprev, hprev);
      hprev = h;
    }

    bool dsame = (Jt == Atile);                // diagonal tile
    bool dcross = (Jt == Atile + NTILE / 2);   // (k, k+N) tile
    float* Rcol = (Atile >= NTILE / 2) ? Rhigh : Rlow;  // col-sum target

#pragma unroll
    for (int nj = 0; nj < 4; ++nj) {
      int row = wbcol + nj * 16 + (l & 15);
      int rx = row & 15;
      const uchar* base = Bs[bi] + row * KDIM;
      f32x4 acc[4] = {};
#pragma unroll
      for (int hf = 0; hf < 2; ++hf) {
        int kb = hf * 8 + 2 * q;                 // even global block index
        i32x4 lo = *(const i32x4*)(base + ((kb ^ rx) << 4));
        i32x4 hi = *(const i32x4*)(base + (((kb + 1) ^ rx) << 4));
        i32x8 bF = __builtin_shufflevector(lo, hi, 0, 1, 2, 3, 4, 5, 6, 7);
#pragma unroll
        for (int mi = 0; mi < 4; ++mi)
          acc[mi] = __builtin_amdgcn_mfma_scale_f32_16x16x128_f8f6f4(
              aF[mi][hf], bF, acc[mi], 0, 0, 0, 0x7F7F7F7F, 0, 0x7F7F7F7F);
      }
      // exp epilogue: row sums + in-lane col partial
      float cs = 0.f;
#pragma unroll
      for (int mi = 0; mi < 4; ++mi)
#pragma unroll
        for (int v = 0; v < 4; ++v) {
          float e = EXP2F(acc[mi][v]);
          rs[mi][v] += e;
          cs += e;
        }
      if (!dsame) {
        // col-sum for col Jt*128 + wbcol + nj*16 + (l&15): reduce over the
        // 4 row-groups (lanes l, l^16, l^32, l^48 hold same col).
        cs += __shfl_xor(cs, 16, 64);
        cs += __shfl_xor(cs, 32, 64);
        if (q == 0)
          atomicAdd(&Rcol[Jt * BM + wbcol + nj * 16 + (l & 15)], cs);
      }

      if (dsame | dcross) {       // wave-uniform, rare
        float* D = dsame ? Dsame : Dcross;
#pragma unroll
        for (int mi = 0; mi < 4; ++mi)
#pragma unroll
          for (int v = 0; v < 4; ++v) {
            int li = warow + mi * 16 + q * 4 + v;
            int lj = wbcol + nj * 16 + (l & 15);
            if (li == lj) D[Atile * BM + li] = acc[mi][v];
          }
      }
    }
  }

  flushrs(Aprev, hprev);  // final row-sum flush
}

// Dsame/Dcross hold acc = (1/tau)*log2e * s. exp(s/tau) = exp2(acc);
// -2*s = -ln2 * acc.  48 blocks x 256 threads = 12288 rows exactly.
__global__ void finalize1_kernel(const float* __restrict__ Rlow,
                                 const float* __restrict__ Rhigh,
                                 const float* __restrict__ Dsame,
                                 const float* __restrict__ Dcross,
                                 float* __restrict__ partial) {
  __shared__ float red[256];
  int k = blockIdx.x * 256 + threadIdx.x;
  float d1 = Rlow[k] + Rhigh[k] - EXP2F(Dsame[k]);
  float d2 = Rhigh[NROWS + k] + Rlow[NROWS + k] - EXP2F(Dsame[NROWS + k]);
  float acc = 0.5f * (logf(d1) + logf(d2)) - LN2F * Dcross[k];
  red[threadIdx.x] = acc;
  __syncthreads();
  for (int s = 128; s > 0; s >>= 1) {
    if (threadIdx.x < s) red[threadIdx.x] += red[threadIdx.x + s];
    __syncthreads();
  }
  if (threadIdx.x == 0) partial[blockIdx.x] = red[0];
}

__global__ void finalize2_kernel(const float* __restrict__ partial,
                                 float* __restrict__ out) {
  float x = (threadIdx.x < FB) ? partial[threadIdx.x] : 0.f;
#pragma unroll
  for (int s = 32; s > 0; s >>= 1) x += __shfl_down(x, s, 64);
  if (threadIdx.x == 0) out[0] = x / (float)NROWS;
}

// ---------------------------------------------------------------------------
extern "C" void kernel_launch(void* const* d_in, const int* in_sizes, int n_in,
                              void* d_out, int out_size, void* d_ws,
                              size_t ws_size, hipStream_t stream) {
  const float* z1 = (const float*)d_in[0];
  const float* z2 = (const float*)d_in[1];
  const float* W1 = (const float*)d_in[2];
  const float* b1 = (const float*)d_in[3];
  const float* W2 = (const float*)d_in[4];
  const float* b2 = (const float*)d_in[5];
  float* out = (float*)d_out;

  char* ws = (char*)d_ws;
  size_t off = 0;
  auto alloc = [&](size_t bytes) -> void* {
    void* p = ws + off;
    off += (bytes + 255) & ~(size_t)255;
    return p;
  };
  __bf16* Zb   = (__bf16*)alloc((size_t)TWO_N * KDIM * 2); // reused as Nq
  __bf16* W1b  = (__bf16*)alloc((size_t)KDIM * KDIM * 2);
  __bf16* W2b  = (__bf16*)alloc((size_t)KDIM * KDIM * 2);
  __bf16* Tb   = (__bf16*)alloc((size_t)TWO_N * KDIM * 2);
  float*  H    = (float*)alloc((size_t)TWO_N * KDIM * 4);
  float*  SS   = (float*)alloc((size_t)TWO_N * 4);
  float*  Rlow = (float*)alloc((size_t)TWO_N * 4);
  float*  Rhigh= (float*)alloc((size_t)TWO_N * 4);
  float*  Dsame= (float*)alloc((size_t)TWO_N * 4);
  float*  Dcross=(float*)alloc((size_t)NROWS * 4);
  float*  partial=(float*)alloc((size_t)FB * 4);
  uchar*  Nq = (uchar*)Zb;  // Zb dead after proj1; fp8 fits in its footprint

  hipMemsetAsync(SS, 0, (size_t)TWO_N * 4, stream);
  hipMemsetAsync(Rlow, 0, (size_t)TWO_N * 4, stream);
  hipMemsetAsync(Rhigh, 0, (size_t)TWO_N * 4, stream);

  int n4z = NROWS * KDIM / 4;   // 786432
  int n4w = KDIM * KDIM / 4;    // 16384
  int n4all = 2 * n4z + 2 * n4w;
  cast_all_kernel<<<(n4all + 255) / 256, 256, 0, stream>>>(z1, z2, W1, W2, Zb,
                                                           W1b, W2b);

  proj1_kernel<<<dim3(TWO_N / BM, KDIM / BN), 256, 0, stream>>>(Zb, W1b, b1, Tb);
  proj2_kernel<<<dim3(TWO_N / BM, KDIM / BN), 256, 0, stream>>>(Tb, W2b, b2, H, SS);

  int n8n = TWO_N * KDIM / 8;   // 786432
  norm_kernel<<<(n8n + 255) / 256, 256, 0, stream>>>(H, SS, Nq);

  sim_kernel<<<PAIRS * SLOTS, 256, 0, stream>>>(Nq, Rlow, Rhigh, Dsame,
                                                Dcross);
  finalize1_kernel<<<FB, 256, 0, stream>>>(Rlow, Rhigh, Dsame, Dcross, partial);
  finalize2_kernel<<<1, 64, 0, stream>>>(partial, out);
}

// Round 7
// 226.382 us; speedup vs baseline: 1.9879x; 1.0507x over previous
//
#include <hip/hip_runtime.h>
#include <hip/hip_bf16.h>
#include <hip/hip_fp8.h>

// ---------------------------------------------------------------------------
// GRACE contrastive loss, MI355X.
//  out = mean_k 0.5*(ln d1_k + ln d2_k) - 2*s12[k,k]
// With M=[n1;n2] (24576x256) everything is row sums of exp(M M^T / tau)
// split by j-half, plus diagonal probes. S is symmetric -> upper-triangle
// tiles only, each feeding row-sums AND col-sums (R12).
//
// R13: de-serialize the R12 col-sum machinery. R12's idle DOUBLED
// (26.5->52.6us): per nj the chain exp->cs->shfl->wait->shfl->wait->atomic
// stalled the wave before the next nj's MFMAs (8 shfl-waits/tile), and the
// __syncthreads vmcnt(0) drain waited on just-issued col atomics.
// Fixes: (1) col partials accumulate in registers (cs4[nj], f32x4); the
// hsum+shfl+atomic for tile f runs at the TOP of iteration f+1 (after the
// stage issue) -> atomics drain a full tile later, 2 shfl-waits per tile
// instead of 8. (2) VALU diet: zero-C MFMA for hf=0 (no 16 acc-init movs),
// f32x4 pk adds for rs/cs, lane-constant LDS addresses hoisted out of the
// nj loop (rx = l&15 is nj-invariant; nj advances via imm offset 4096).
// Geometry unchanged from R12: pairs (I,191-I), 96x16 grid, 2x32KB LDS
// dbuf, XOR-swizzled staging, launch_bounds(256,2).
// ---------------------------------------------------------------------------

#define NROWS 12288
#define TWO_N 24576
#define KDIM 256
#define BM 128
#define BN 128
#define BK 32
#define BJ 128
#define NTILE 192   /* 24576 / 128 row-tiles */
#define PAIRS 96
#define SLOTS 16
#define FB 48                   /* finalize partial blocks */
#define LOG2E 1.4426950408889634f
#define SIMSCALE 1.6986436f     /* sqrt(2*log2(e)); acc = (1/tau)*log2e*s */
#define LN2F 0.6931471805599453f

#if __has_builtin(__builtin_amdgcn_exp2f)
#define EXP2F(x) __builtin_amdgcn_exp2f(x)
#else
#define EXP2F(x) exp2f(x)
#endif

typedef __bf16 bf16x8 __attribute__((ext_vector_type(8)));
typedef __bf16 bf16x4v __attribute__((ext_vector_type(4)));
typedef float f32x4 __attribute__((ext_vector_type(4)));
typedef int i32x4 __attribute__((ext_vector_type(4)));
typedef int i32x8 __attribute__((ext_vector_type(8)));
typedef unsigned char uchar;

typedef const __attribute__((address_space(1))) void* gptr_t;
typedef __attribute__((address_space(3))) void* lptr_t;

// ======== legacy 128x128 bf16 GEMM core (proj1/proj2 only) ================
__device__ __forceinline__ void stage_slab(const __bf16* g, int row0, int kelem,
                                           __bf16* lds, int w, int l) {
#pragma unroll
  for (int t = 0; t < 2; ++t) {
    int chunk = w * 2 + t;
    int r = chunk * 16 + (l >> 2);
    int c = l & 3;
    int src = c ^ (r & 3);
    const __bf16* ga = g + (size_t)(row0 + r) * KDIM + kelem + src * 8;
    __bf16* la = lds + chunk * 512;
    __builtin_amdgcn_global_load_lds((gptr_t)ga, (lptr_t)la, 16, 0, 0);
  }
}

__device__ __forceinline__ bf16x8 read_frag(const __bf16* lds, int rowbase,
                                            int tile, int l) {
  int r = rowbase + tile * 16 + (l & 15);
  int q = l >> 4;
  int blk = q ^ (r & 3);
  return *(const bf16x8*)(lds + r * 32 + blk * 8);
}

__device__ __forceinline__ void gemm_tile_core(const __bf16* A, int arow0,
                                               const __bf16* B, int brow0,
                                               __bf16* As, __bf16* Bs,
                                               f32x4 (&acc)[4][4], int w, int l) {
  const int warow = (w >> 1) * 64;
  const int wbrow = (w & 1) * 64;
#pragma unroll
  for (int ks = 0; ks < KDIM / BK; ++ks) {
    __syncthreads();
    stage_slab(A, arow0, ks * BK, As, w, l);
    stage_slab(B, brow0, ks * BK, Bs, w, l);
    __syncthreads();
    bf16x8 aF[4], bF[4];
#pragma unroll
    for (int mi = 0; mi < 4; ++mi) aF[mi] = read_frag(As, warow, mi, l);
#pragma unroll
    for (int ni = 0; ni < 4; ++ni) bF[ni] = read_frag(Bs, wbrow, ni, l);
#pragma unroll
    for (int mi = 0; mi < 4; ++mi)
#pragma unroll
      for (int ni = 0; ni < 4; ++ni)
        acc[mi][ni] = __builtin_amdgcn_mfma_f32_16x16x32_bf16(
            aF[mi], bF[ni], acc[mi][ni], 0, 0, 0);
  }
}

// ---------------------------------------------------------------------------
// one launch: cast z1, z2, W1, W2 to bf16 (float4 granules)
__global__ void cast_all_kernel(const float* __restrict__ z1,
                                const float* __restrict__ z2,
                                const float* __restrict__ W1,
                                const float* __restrict__ W2,
                                __bf16* __restrict__ Zb,
                                __bf16* __restrict__ W1b,
                                __bf16* __restrict__ W2b) {
  const int n4z = NROWS * KDIM / 4;  // 786432
  const int n4w = KDIM * KDIM / 4;   // 16384
  int i = blockIdx.x * blockDim.x + threadIdx.x;
  const float* src;
  __bf16* dst;
  int j;
  if (i < n4z) {
    src = z1; dst = Zb; j = i;
  } else if (i < 2 * n4z) {
    src = z2; dst = Zb + (size_t)NROWS * KDIM; j = i - n4z;
  } else if (i < 2 * n4z + n4w) {
    src = W1; dst = W1b; j = i - 2 * n4z;
  } else if (i < 2 * n4z + 2 * n4w) {
    src = W2; dst = W2b; j = i - 2 * n4z - n4w;
  } else {
    return;
  }
  float4 v = *(const float4*)(src + (size_t)j * 4);
  bf16x4v o;
  o[0] = (__bf16)v.x; o[1] = (__bf16)v.y; o[2] = (__bf16)v.z; o[3] = (__bf16)v.w;
  *(bf16x4v*)(dst + (size_t)j * 4) = o;
}

// T = ELU(Z @ W1^T + b1), stored bf16
__global__ __launch_bounds__(256, 2) void proj1_kernel(
    const __bf16* __restrict__ Zb, const __bf16* __restrict__ W1b,
    const float* __restrict__ b1, __bf16* __restrict__ Tb) {
  __shared__ __align__(16) __bf16 As[BM * BK];
  __shared__ __align__(16) __bf16 Bs[BN * BK];
  int w = threadIdx.x >> 6, l = threadIdx.x & 63;
  int i0 = blockIdx.x * BM, j0 = blockIdx.y * BN;
  int warow = (w >> 1) * 64, wbrow = (w & 1) * 64;
  f32x4 acc[4][4] = {};
  gemm_tile_core(Zb, i0, W1b, j0, As, Bs, acc, w, l);
  float bias[4];
#pragma unroll
  for (int ni = 0; ni < 4; ++ni) bias[ni] = b1[j0 + wbrow + ni * 16 + (l & 15)];
#pragma unroll
  for (int mi = 0; mi < 4; ++mi)
#pragma unroll
    for (int ni = 0; ni < 4; ++ni)
#pragma unroll
      for (int v = 0; v < 4; ++v) {
        int row = i0 + warow + mi * 16 + (l >> 4) * 4 + v;
        int col = j0 + wbrow + ni * 16 + (l & 15);
        float x = acc[mi][ni][v] + bias[ni];
        x = x > 0.f ? x : (EXP2F(x * LOG2E) - 1.f);  // ELU
        Tb[(size_t)row * KDIM + col] = (__bf16)x;
      }
}

// H = T @ W2^T + b2 (fp32), plus per-row sum of squares via atomics
__global__ __launch_bounds__(256, 2) void proj2_kernel(
    const __bf16* __restrict__ Tb, const __bf16* __restrict__ W2b,
    const float* __restrict__ b2, float* __restrict__ H,
    float* __restrict__ SS) {
  __shared__ __align__(16) __bf16 As[BM * BK];
  __shared__ __align__(16) __bf16 Bs[BN * BK];
  int w = threadIdx.x >> 6, l = threadIdx.x & 63;
  int i0 = blockIdx.x * BM, j0 = blockIdx.y * BN;
  int warow = (w >> 1) * 64, wbrow = (w & 1) * 64;
  f32x4 acc[4][4] = {};
  gemm_tile_core(Tb, i0, W2b, j0, As, Bs, acc, w, l);
  float bias[4];
#pragma unroll
  for (int ni = 0; ni < 4; ++ni) bias[ni] = b2[j0 + wbrow + ni * 16 + (l & 15)];
  float ss[4][4] = {};
#pragma unroll
  for (int mi = 0; mi < 4; ++mi)
#pragma unroll
    for (int ni = 0; ni < 4; ++ni)
#pragma unroll
      for (int v = 0; v < 4; ++v) {
        int row = i0 + warow + mi * 16 + (l >> 4) * 4 + v;
        int col = j0 + wbrow + ni * 16 + (l & 15);
        float x = acc[mi][ni][v] + bias[ni];
        H[(size_t)row * KDIM + col] = x;
        ss[mi][v] += x * x;
      }
#pragma unroll
  for (int mi = 0; mi < 4; ++mi)
#pragma unroll
    for (int v = 0; v < 4; ++v) {
      float x = ss[mi][v];
      x += __shfl_xor(x, 1, 64);
      x += __shfl_xor(x, 2, 64);
      x += __shfl_xor(x, 4, 64);
      x += __shfl_xor(x, 8, 64);
      if ((l & 15) == 0)
        atomicAdd(&SS[i0 + warow + mi * 16 + (l >> 4) * 4 + v], x);
    }
}

// pack 4 floats -> 4 fp8 e4m3 bytes
__device__ __forceinline__ unsigned int pack4_fp8(float a, float b, float c,
                                                  float d) {
#if __has_builtin(__builtin_amdgcn_cvt_pk_fp8_f32)
  int v = 0;
  v = __builtin_amdgcn_cvt_pk_fp8_f32(a, b, v, false);
  v = __builtin_amdgcn_cvt_pk_fp8_f32(c, d, v, true);
  return (unsigned int)v;
#else
  __hip_fp8_e4m3 qa(a), qb(b), qc(c), qd(d);
  return (unsigned int)qa.__x | ((unsigned int)qb.__x << 8) |
         ((unsigned int)qc.__x << 16) | ((unsigned int)qd.__x << 24);
#endif
}

// Nq = fp8(H * rsqrt(SS[row]) * SIMSCALE) — 8 elements per thread.
// SIMSCALE folds the (1/tau)*log2(e) exponent scale into the data:
// dot(Nq_i, Nq_j) = 2.8854 * cos_ij, so exp2(acc) = exp(cos/tau).
__global__ void norm_kernel(const float* __restrict__ H,
                            const float* __restrict__ SS,
                            uchar* __restrict__ Nq) {
  int i = blockIdx.x * blockDim.x + threadIdx.x;
  size_t idx = (size_t)i * 8;
  if (idx >= (size_t)TWO_N * KDIM) return;
  int row = (int)(idx >> 8);
  float inv = rsqrtf(SS[row]) * SIMSCALE;
  float4 h0 = *(const float4*)(H + idx);
  float4 h1 = *(const float4*)(H + idx + 4);
  uint2 o;
  o.x = pack4_fp8(h0.x * inv, h0.y * inv, h0.z * inv, h0.w * inv);
  o.y = pack4_fp8(h1.x * inv, h1.y * inv, h1.z * inv, h1.w * inv);
  *(uint2*)(Nq + idx) = o;
}

// ======== R13 sim kernel: upper-triangle, deferred col-sums ================
// Pair p = (I1=p, I2=191-p): flattened F in [0,193):
//   F <  L1=192-I1 : A-tile = I1, J-tile = I1 + F   (seg1)
//   F >= L1        : A-tile = I2, J-tile = F - 1    (seg2)
// Off-diag tile: row-sums (registers, flushed on half/segment switch) and
// col-sums (cs4[nj] registers; hsum+shfl+atomic DEFERRED to the top of the
// next iteration so the shfl-waits sit behind the stage issue and the
// atomics drain a full tile later). Diag tile: row-sums only.
__global__ __launch_bounds__(256, 2) void sim_kernel(
    const uchar* __restrict__ Nq, float* __restrict__ Rlow,
    float* __restrict__ Rhigh, float* __restrict__ Dsame,
    float* __restrict__ Dcross) {
  __shared__ __align__(16) uchar Bs[2][BJ * KDIM];  // 2 x 32KB
  int tid = threadIdx.x;
  int w = tid >> 6, l = tid & 63;
  int q = l >> 4;
  int rx = l & 15;
  int b = blockIdx.x;
  int p = b >> 4;              // pair index 0..95
  int s = b & 15;              // slot within pair
  const int I1 = p, I2 = NTILE - 1 - p;
  const int L1 = NTILE - I1;   // seg1 length
  int fstart = (s == 0) ? 0 : 13 + (s - 1) * 12;
  int fend = fstart + ((s == 0) ? 13 : 12);
  int warow = (w >> 1) * 64;   // A rows of this wave
  int wbcol = (w & 1) * 64;    // B cols of this wave

  // per-lane staging offsets within a 128x256B tile (source-side XOR
  // swizzle: LDS slot c of row r holds global 16B-block c ^ (r&15)).
  unsigned off0[8];
#pragma unroll
  for (int t = 0; t < 8; ++t) {
    int ch = w * 8 + t;            // wave-uniform chunk 0..31 (1KB each)
    int r = ch * 4 + (l >> 4);     // row 0..127 (4 rows per chunk)
    int c = l & 15;                // dest 16B-block slot
    int src = c ^ (r & 15);        // global k-block landing in slot c
    off0[t] = (unsigned)(r * KDIM + src * 16);
  }
  auto jtile_of = [&](int F) { return (F < L1) ? (I1 + F) : (F - 1); };
  auto atile_of = [&](int F) { return (F < L1) ? I1 : I2; };

  auto stage = [&](int F, int bi) {
    unsigned jo = (unsigned)(jtile_of(F) * (BM * KDIM));
#pragma unroll
    for (int t = 0; t < 8; ++t) {
      const uchar* ga = Nq + (size_t)(jo + off0[t]);
      uchar* la = Bs[bi] + (w * 8 + t) * 1024;  // wave-uniform base
      __builtin_amdgcn_global_load_lds((gptr_t)ga, (lptr_t)la, 16, 0, 0);
    }
  };

  // ---- A fragments: aF[mi][hf], 8 x i32x8 = 64 VGPRs ----
  i32x8 aF[4][2];
  auto load_aF = [&](int Atile) {
#pragma unroll
    for (int mi = 0; mi < 4; ++mi) {
      const uchar* ap = Nq +
          (size_t)(Atile * BM + warow + mi * 16 + rx) * KDIM + q * 32;
#pragma unroll
      for (int hf = 0; hf < 2; ++hf)
        aF[mi][hf] = *(const i32x8*)(ap + hf * 128);
    }
  };

  // lane-constant LDS read offsets for the B fragments (rx = l&15 is
  // nj-invariant; nj advances by 16 rows = 4096 bytes, an imm offset).
  int rdo[2][2];
#pragma unroll
  for (int hf = 0; hf < 2; ++hf) {
    int kb = hf * 8 + 2 * q;
    rdo[hf][0] = (kb ^ rx) << 4;
    rdo[hf][1] = ((kb + 1) ^ rx) << 4;
  }

  f32x4 rs4[4] = {};  // running row sums for current (A, half(J)) span
  f32x4 cs4[4];       // col partials of the pending tile
  int pend = 0;       // pending col-sum flush?
  float* pendR = nullptr;
  int pendBase = 0;

  auto flushrs = [&](int Atile, int h) {
    float* R = h ? Rhigh : Rlow;
#pragma unroll
    for (int mi = 0; mi < 4; ++mi)
#pragma unroll
      for (int v = 0; v < 4; ++v) {
        float x = rs4[mi][v];
        x += __shfl_xor(x, 1, 64);
        x += __shfl_xor(x, 2, 64);
        x += __shfl_xor(x, 4, 64);
        x += __shfl_xor(x, 8, 64);
        if (rx == 0)
          atomicAdd(&R[Atile * BM + warow + mi * 16 + q * 4 + v], x);
        rs4[mi][v] = 0.f;
      }
  };
  auto flushcs = [&]() {
#pragma unroll
    for (int nj = 0; nj < 4; ++nj) {
      float c = (cs4[nj][0] + cs4[nj][1]) + (cs4[nj][2] + cs4[nj][3]);
      c += __shfl_xor(c, 16, 64);
      c += __shfl_xor(c, 32, 64);
      if (q == 0)
        atomicAdd(&pendR[pendBase + wbcol + nj * 16 + rx], c);
    }
    pend = 0;
  };

  const f32x4 Z4 = {0.f, 0.f, 0.f, 0.f};

  int Aprev = atile_of(fstart);
  int hprev = (jtile_of(fstart) >= NTILE / 2) ? 1 : 0;
  load_aF(Aprev);
  stage(fstart, 0);  // prologue

  for (int f = fstart; f < fend; ++f) {
    int bi = (f - fstart) & 1;
    __syncthreads();                       // stage(f) done; prev readers done
    if (f + 1 < fend) stage(f + 1, bi ^ 1);  // drains at NEXT barrier
    if (pend) flushcs();  // tile f-1's col-sums; atomics drain at barrier f+1

    int Atile = atile_of(f);
    int Jt = jtile_of(f);
    int h = (Jt >= NTILE / 2) ? 1 : 0;
    if (Atile != Aprev) {          // segment switch (<=1 per block)
      flushrs(Aprev, hprev);
      load_aF(Atile);
      Aprev = Atile;
      hprev = h;
    } else if (h != hprev) {       // half(J) crossing (<=1 per segment)
      flushrs(Aprev, hprev);
      hprev = h;
    }

    bool dsame = (Jt == Atile);                // diagonal tile
    bool dcross = (Jt == Atile + NTILE / 2);   // (k, k+N) tile
    float* Rcol = (Atile >= NTILE / 2) ? Rhigh : Rlow;  // col-sum target

    // tile-constant B-fragment pointers (nj advances via imm offset 4096)
    const uchar* bL = Bs[bi] + (size_t)(wbcol + rx) * KDIM;
    const uchar* p00 = bL + rdo[0][0];
    const uchar* p01 = bL + rdo[0][1];
    const uchar* p10 = bL + rdo[1][0];
    const uchar* p11 = bL + rdo[1][1];

#pragma unroll
    for (int nj = 0; nj < 4; ++nj) {
      const int no = nj * 4096;
      i32x8 bF0 = __builtin_shufflevector(*(const i32x4*)(p00 + no),
                                          *(const i32x4*)(p01 + no),
                                          0, 1, 2, 3, 4, 5, 6, 7);
      i32x8 bF1 = __builtin_shufflevector(*(const i32x4*)(p10 + no),
                                          *(const i32x4*)(p11 + no),
                                          0, 1, 2, 3, 4, 5, 6, 7);
      f32x4 acc[4];
#pragma unroll
      for (int mi = 0; mi < 4; ++mi)
        acc[mi] = __builtin_amdgcn_mfma_scale_f32_16x16x128_f8f6f4(
            aF[mi][0], bF0, Z4, 0, 0, 0, 0x7F7F7F7F, 0, 0x7F7F7F7F);
#pragma unroll
      for (int mi = 0; mi < 4; ++mi)
        acc[mi] = __builtin_amdgcn_mfma_scale_f32_16x16x128_f8f6f4(
            aF[mi][1], bF1, acc[mi], 0, 0, 0, 0x7F7F7F7F, 0, 0x7F7F7F7F);
      // exp epilogue: vector adds (pk) into row sums + col partials
#pragma unroll
      for (int mi = 0; mi < 4; ++mi) {
        f32x4 e4;
        e4[0] = EXP2F(acc[mi][0]);
        e4[1] = EXP2F(acc[mi][1]);
        e4[2] = EXP2F(acc[mi][2]);
        e4[3] = EXP2F(acc[mi][3]);
        rs4[mi] += e4;
        cs4[nj] = (mi == 0) ? e4 : (cs4[nj] + e4);
      }

      if (dsame | dcross) {       // wave-uniform, rare
        float* D = dsame ? Dsame : Dcross;
#pragma unroll
        for (int mi = 0; mi < 4; ++mi)
#pragma unroll
          for (int v = 0; v < 4; ++v) {
            int li = warow + mi * 16 + q * 4 + v;
            int lj = wbcol + nj * 16 + rx;
            if (li == lj) D[Atile * BM + li] = acc[mi][v];
          }
      }
    }

    if (!dsame) {  // schedule this tile's col-sums for the next iteration
      pend = 1;
      pendR = Rcol;
      pendBase = Jt * BM;
    }
  }

  if (pend) flushcs();    // last tile's col-sums
  flushrs(Aprev, hprev);  // final row-sum flush
}

// Dsame/Dcross hold acc = (1/tau)*log2e * s. exp(s/tau) = exp2(acc);
// -2*s = -ln2 * acc.  48 blocks x 256 threads = 12288 rows exactly.
__global__ void finalize1_kernel(const float* __restrict__ Rlow,
                                 const float* __restrict__ Rhigh,
                                 const float* __restrict__ Dsame,
                                 const float* __restrict__ Dcross,
                                 float* __restrict__ partial) {
  __shared__ float red[256];
  int k = blockIdx.x * 256 + threadIdx.x;
  float d1 = Rlow[k] + Rhigh[k] - EXP2F(Dsame[k]);
  float d2 = Rhigh[NROWS + k] + Rlow[NROWS + k] - EXP2F(Dsame[NROWS + k]);
  float acc = 0.5f * (logf(d1) + logf(d2)) - LN2F * Dcross[k];
  red[threadIdx.x] = acc;
  __syncthreads();
  for (int s = 128; s > 0; s >>= 1) {
    if (threadIdx.x < s) red[threadIdx.x] += red[threadIdx.x + s];
    __syncthreads();
  }
  if (threadIdx.x == 0) partial[blockIdx.x] = red[0];
}

__global__ void finalize2_kernel(const float* __restrict__ partial,
                                 float* __restrict__ out) {
  float x = (threadIdx.x < FB) ? partial[threadIdx.x] : 0.f;
#pragma unroll
  for (int s = 32; s > 0; s >>= 1) x += __shfl_down(x, s, 64);
  if (threadIdx.x == 0) out[0] = x / (float)NROWS;
}

// ---------------------------------------------------------------------------
extern "C" void kernel_launch(void* const* d_in, const int* in_sizes, int n_in,
                              void* d_out, int out_size, void* d_ws,
                              size_t ws_size, hipStream_t stream) {
  const float* z1 = (const float*)d_in[0];
  const float* z2 = (const float*)d_in[1];
  const float* W1 = (const float*)d_in[2];
  const float* b1 = (const float*)d_in[3];
  const float* W2 = (const float*)d_in[4];
  const float* b2 = (const float*)d_in[5];
  float* out = (float*)d_out;

  char* ws = (char*)d_ws;
  size_t off = 0;
  auto alloc = [&](size_t bytes) -> void* {
    void* p = ws + off;
    off += (bytes + 255) & ~(size_t)255;
    return p;
  };
  __bf16* Zb   = (__bf16*)alloc((size_t)TWO_N * KDIM * 2); // reused as Nq
  __bf16* W1b  = (__bf16*)alloc((size_t)KDIM * KDIM * 2);
  __bf16* W2b  = (__bf16*)alloc((size_t)KDIM * KDIM * 2);
  __bf16* Tb   = (__bf16*)alloc((size_t)TWO_N * KDIM * 2);
  float*  H    = (float*)alloc((size_t)TWO_N * KDIM * 4);
  float*  SS   = (float*)alloc((size_t)TWO_N * 4);
  float*  Rlow = (float*)alloc((size_t)TWO_N * 4);
  float*  Rhigh= (float*)alloc((size_t)TWO_N * 4);
  float*  Dsame= (float*)alloc((size_t)TWO_N * 4);
  float*  Dcross=(float*)alloc((size_t)NROWS * 4);
  float*  partial=(float*)alloc((size_t)FB * 4);
  uchar*  Nq = (uchar*)Zb;  // Zb dead after proj1; fp8 fits in its footprint

  hipMemsetAsync(SS, 0, (size_t)TWO_N * 4, stream);
  hipMemsetAsync(Rlow, 0, (size_t)TWO_N * 4, stream);
  hipMemsetAsync(Rhigh, 0, (size_t)TWO_N * 4, stream);

  int n4z = NROWS * KDIM / 4;   // 786432
  int n4w = KDIM * KDIM / 4;    // 16384
  int n4all = 2 * n4z + 2 * n4w;
  cast_all_kernel<<<(n4all + 255) / 256, 256, 0, stream>>>(z1, z2, W1, W2, Zb,
                                                           W1b, W2b);

  proj1_kernel<<<dim3(TWO_N / BM, KDIM / BN), 256, 0, stream>>>(Zb, W1b, b1, Tb);
  proj2_kernel<<<dim3(TWO_N / BM, KDIM / BN), 256, 0, stream>>>(Tb, W2b, b2, H, SS);

  int n8n = TWO_N * KDIM / 8;   // 786432
  norm_kernel<<<(n8n + 255) / 256, 256, 0, stream>>>(H, SS, Nq);

  sim_kernel<<<PAIRS * SLOTS, 256, 0, stream>>>(Nq, Rlow, Rhigh, Dsame,
                                                Dcross);
  finalize1_kernel<<<FB, 256, 0, stream>>>(Rlow, Rhigh, Dsame, Dcross, partial);
  finalize2_kernel<<<1, 64, 0, stream>>>(partial, out);
}